// Round 7
// baseline (1179.937 us; speedup 1.0000x reference)
//
#include <hip/hip_runtime.h>
#include <math.h>

#define CAPT 20480              // per-type compacted-node capacity (actual ~16.7k)
#define R2   (2*CAPT)

typedef __attribute__((ext_vector_type(8))) short short8;
typedef __attribute__((ext_vector_type(4))) float f32x4;

// ---- fast transcendentals: v_exp_f32 / v_rcp_f32 based; err ~1e-7 << bf16 ulp ----
__device__ __forceinline__ float fexp2_(float x){ return __builtin_amdgcn_exp2f(x); }
__device__ __forceinline__ float frcp_(float x){ return __builtin_amdgcn_rcpf(x); }
__device__ __forceinline__ float ftanh_(float x){
  float ax = __builtin_fabsf(x);
  float t = fexp2_(-2.885390082f * ax);          // e^{-2|x|}
  float r = (1.f - t) * frcp_(1.f + t);
  return __builtin_copysignf(r, x);
}
__device__ __forceinline__ float fsig_(float x){
  return frcp_(1.f + fexp2_(-1.442695041f * x));
}
__device__ __forceinline__ float fgelu_(float x){
  const float c = 0.7978845608028654f;
  return 0.5f*x*(1.f + ftanh_(c*(x + 0.044715f*x*x*x)));
}
__device__ __forceinline__ unsigned short f2bf(float x){
  unsigned int u = __float_as_uint(x);
  return (unsigned short)((u + 0x7FFFu + ((u>>16)&1u)) >> 16);
}
__device__ __forceinline__ float bf2f(unsigned short v){
  return __uint_as_float(((unsigned int)v) << 16);
}

// ---------------- weight prep: transposed bf16 B arena, padded to 16-mult segments ----
// Arena layout (bf16 elems):
//  [0..6)      plain msg li:  [160][96]   off = li*15360
//  [6..12)     plain upd li:  [80][160]   off = 92160 + li*12800
//  [12..14)    ar msg blk:    [320][160]  off = 168960 + blk*51200
//  [14..16)    ar upd blk:    [80][320]   off = 271360 + blk*25600
//  [16..18)    gru typ:       [256][128]  off = 322560 + typ*32768
__global__ void k_prepB(const float* __restrict__ Wm_plain, const float* __restrict__ Wu_plain,
                        const float* __restrict__ Wm_ar, const float* __restrict__ Wu_ar,
                        const float* __restrict__ Wi_map, const float* __restrict__ Wh_map,
                        const float* __restrict__ Wi_mem, const float* __restrict__ Wh_mem,
                        unsigned short* __restrict__ BtArena){
  int id = blockIdx.y;
  int Kp, elems, off;
  if (id < 6){ Kp=96;  elems=15360; off=id*15360; }
  else if (id < 12){ Kp=160; elems=12800; off=92160+(id-6)*12800; }
  else if (id < 14){ Kp=160; elems=51200; off=168960+(id-12)*51200; }
  else if (id < 16){ Kp=320; elems=25600; off=271360+(id-14)*25600; }
  else { Kp=128; elems=32768; off=322560+(id-16)*32768; }
  for (int g = blockIdx.x*256 + threadIdx.x; g < elems; g += 8*256){
    int c = g / Kp, k = g - c*Kp;
    float val = 0.f;
    if (id < 6){
      int li = id; int t = (c >= 80); int cc = c - t*80;
      if (cc < 70 && k < 70) val = Wm_plain[((li*2+t)*70 + k)*70 + cc];
    } else if (id < 12){
      int li = id-6;
      int kk = (k < 70) ? k : ((k >= 80 && k < 150) ? 70 + (k-80) : -1);
      if (c < 70 && kk >= 0) val = Wu_plain[(li*140 + kk)*70 + c];
    } else if (id < 14){
      int blk = id-12; int t = (c >= 160); int cc = c - t*160;
      int kk = (k < 70) ? k : ((k >= 80 && k < 150) ? 70 + (k-80) : -1);
      if (cc < 140 && kk >= 0) val = Wm_ar[(((blk*2+t)*140) + kk)*140 + cc];
    } else if (id < 16){
      int blk = id-14;
      int kk = (k < 70) ? k : ((k >= 80 && k < 150) ? 70 + (k-80)
               : ((k >= 160 && k < 300) ? 140 + (k-160) : -1));
      if (c < 70 && kk >= 0) val = Wu_ar[(blk*280 + kk)*70 + c];
    } else {
      int typ = id-16;
      const float* Wi = typ ? Wi_mem : Wi_map;
      const float* Wh = typ ? Wh_mem : Wh_map;
      if (c < 192) val = (k < 64) ? Wi[c*64 + k] : Wh[c*64 + (k-64)];
      else { int cc = c-192; val = (k >= 64) ? Wh[(128+cc)*64 + (k-64)] : 0.f; }
    }
    BtArena[off + g] = f2bf(val);
  }
}

// bias arena (fp32): [0..960) plain msg [160]x6; [960..1440) plain upd [80]x6;
// [1440..2080) ar msg [320]x2; [2080..2240) ar upd [80]x2; [2240..2752) gru [256]x2
__global__ void k_prepBias(const float* __restrict__ bm_plain, const float* __restrict__ bu_plain,
                           const float* __restrict__ bm_ar, const float* __restrict__ bu_ar,
                           const float* __restrict__ bi_map, const float* __restrict__ bh_map,
                           const float* __restrict__ bi_mem, const float* __restrict__ bh_mem,
                           float* __restrict__ biasA){
  for (int g = threadIdx.x; g < 2752; g += 256){
    float val = 0.f;
    if (g < 960){ int li=g/160, c=g%160; int t=(c>=80); int cc=c-t*80;
      if (cc<70) val = bm_plain[(li*2+t)*70 + cc]; }
    else if (g < 1440){ int u=g-960; int li=u/80, c=u%80; if (c<70) val = bu_plain[li*70+c]; }
    else if (g < 2080){ int u=g-1440; int blk=u/320, c=u%320; int t=(c>=160); int cc=c-t*160;
      if (cc<140) val = bm_ar[(blk*2+t)*140 + cc]; }
    else if (g < 2240){ int u=g-2080; int blk=u/80, c=u%80; if (c<70) val = bu_ar[blk*70+c]; }
    else { int u=g-2240; int typ=u/256, c=u%256;
      const float* bi = typ ? bi_mem : bi_map; const float* bh = typ ? bh_mem : bh_map;
      val = (c < 192) ? (bi[c]+bh[c]) : bh[128 + (c-192)]; }
    biasA[g] = val;
  }
}

// ---------------- embed -> bf16 table (1.28 MB, L2-resident for the gather) ----------
__global__ void k_prepEmb(const float* __restrict__ embed, unsigned short* __restrict__ embB,
                          int total){
  int g = blockIdx.x*256 + threadIdx.x;
  if (g < total) embB[g] = f2bf(embed[g]);
}

// ---------------- init h = [one_hot(type,6) | zeros] bf16, stride 80 ----------------
__global__ void k_init_h(const int* __restrict__ type_idx, unsigned short* __restrict__ h, int N){
  int g = blockIdx.x*256 + threadIdx.x;
  if (g >= N*80) return;
  int n = g / 80, c = g - n*80;
  h[g] = (c < 6 && type_idx[n] == c) ? (unsigned short)0x3F80 : (unsigned short)0;
}

__global__ void k_compact(const int* __restrict__ type_idx, int* __restrict__ idxcat,
                          int* __restrict__ cnt, int N){
  int n = blockIdx.x*256 + threadIdx.x;
  if (n >= N) return;
  int t = type_idx[n];
  if (t == 0){ int p = atomicAdd(&cnt[0],1); if (p < CAPT) idxcat[p] = n; }
  else if (t == 5){ int p = atomicAdd(&cnt[1],1); if (p < CAPT) idxcat[CAPT+p] = n; }
}

// ---------------- CSR build, per-node edge count padded to multiple of 4 -------------
__global__ void k_count(const int* __restrict__ edst, int* __restrict__ deg, int TE){
  int i = blockIdx.x*256 + threadIdx.x;
  if (i < TE) atomicAdd(&deg[edst[i]], 1);
}
__global__ void k_scan1(const int* __restrict__ deg, int* __restrict__ off,
                        int* __restrict__ bsum, int N){
  __shared__ int sh[256];
  int t = threadIdx.x; int base = blockIdx.x*2048;
  int v[8]; int s = 0;
  for (int i=0;i<8;i++){
    int g = base + t*8 + i;
    int x = (g<N)? (((deg[g]+3)>>2)<<2) : 0;     // pad to x4
    v[i]=x; s+=x;
  }
  sh[t]=s; __syncthreads();
  for (int o=1;o<256;o<<=1){ int x = (t>=o)? sh[t-o]:0; __syncthreads(); sh[t]+=x; __syncthreads(); }
  if (t==255) bsum[blockIdx.x] = sh[255];
  int run = sh[t]-s;
  for (int i=0;i<8;i++){ int g = base + t*8 + i; if (g<N) off[g]=run; run+=v[i]; }
}
__global__ void k_scan2(int* bsum, int nb){
  if (threadIdx.x==0 && blockIdx.x==0){
    int run=0;
    for(int b=0;b<nb;b++){ int x=bsum[b]; bsum[b]=run; run+=x; }
    bsum[nb]=run;                                 // grand total (padded)
  }
}
__global__ void k_scan3(int* __restrict__ off, const int* __restrict__ bsum, int N, int nb){
  int g = blockIdx.x*256+threadIdx.x;
  if (g < N) off[g] += bsum[g>>11];
  if (g == 0) off[N] = bsum[nb];
}
__global__ void k_fill(const int* __restrict__ esrc, const int* __restrict__ edst,
                       const int* __restrict__ off, int* __restrict__ cur,
                       int* __restrict__ edata, int TE, int E){
  int i = blockIdx.x*256 + threadIdx.x;
  if (i >= TE) return;
  int d = edst[i];
  int pos = off[d] + atomicAdd(&cur[d], 1);
  edata[pos] = (esrc[i] << 1) | (i >= E ? 1 : 0);
}
// pad slots [deg, deg4) with a duplicate of the node's first edge (idempotent for max)
__global__ void k_pad(const int* __restrict__ off, const int* __restrict__ cur,
                      int* __restrict__ edata, int N){
  int n = blockIdx.x*256 + threadIdx.x;
  if (n >= N) return;
  int d = cur[n];
  if (d == 0) return;
  int d4 = ((d+3)>>2)<<2;
  int base = off[n];
  int first = edata[base];
  for (int i = d; i < d4; i++) edata[base+i] = first;
}

// ======== kgru: persistent GRU — all 8 steps in one launch, H lives in LDS =========
// Block = 64 rows of the compacted region blockIdx.y (0=map, 1=mem).
// A-tile As[64][128] = [x_s (embB gather) | H]; B in regs (wave w owns col tiles
// {w,w+4,w+8,w+12} == (r,z,n,hn) for u=16w+m). h' -> bf16 -> LDS H (next step) or
// scatter to h[idx*80+6+u] (last step). Numerics identical to the 8-launch version.
__global__ __launch_bounds__(256) void kgru(
    const int* __restrict__ idxcat, const int* __restrict__ tokens,
    const unsigned short* __restrict__ embB,
    const unsigned short* __restrict__ Bt, const unsigned short* __restrict__ Bt2,
    const float* __restrict__ bias, const float* __restrict__ bias2,
    unsigned short* __restrict__ hOut)
{
  __shared__ __align__(16) unsigned short As[64*128];
  __shared__ int tokS[64*8];
  __shared__ int idxS[64];
  int rb = blockIdx.y * CAPT + blockIdx.x * 64;
  if (idxcat[rb] < 0) return;                      // all-pad block
  int t = threadIdx.x;
  int lane = t & 63, m = lane & 15, q = lane >> 4, w = t >> 6;
  const unsigned short* Bsel = blockIdx.y ? Bt2 : Bt;
  const float* bsel = blockIdx.y ? bias2 : bias;
  short8 breg[4][4]; float bv[4];
  #pragma unroll
  for (int j=0;j<4;j++){
    int col = (w + 4*j)*16 + m;
    bv[j] = bsel[col];
    #pragma unroll
    for (int kt=0;kt<4;kt++)
      breg[j][kt] = *(const short8*)&Bsel[(size_t)col*128 + kt*32 + q*8];
  }
  if (t < 64) idxS[t] = idxcat[rb + t];
  for (int j = t; j < 512; j += 256){
    int nd = idxcat[rb + (j>>3)]; if (nd < 0) nd = 0;
    tokS[j] = tokens[nd*8 + (j & 7)];
  }
  for (int j = t; j < 2048; j += 256){             // zero H region
    int row = j >> 5, uu = (j & 31)*2;
    *(unsigned int*)&As[row*128 + 64 + uu] = 0;
  }
  __syncthreads();
  int u = w*16 + m;
  for (int s = 0; s < 8; s++){
    uint4 xr[2];
    #pragma unroll
    for (int i=0;i<2;i++){
      int j = t + i*256;
      int row = j >> 3, ch = j & 7;
      int tok = tokS[row*8 + s];
      xr[i] = *(const uint4*)&embB[(size_t)tok*64 + ch*8];
    }
    __syncthreads();                               // prior step's LDS reads done
    #pragma unroll
    for (int i=0;i<2;i++){
      int j = t + i*256;
      int row = j >> 3, ch = j & 7;
      *(uint4*)&As[row*128 + ch*8] = xr[i];
    }
    __syncthreads();                               // X_s + H_s ready
    f32x4 acc[4][4] = {};
    #pragma unroll
    for (int kt=0;kt<4;kt++){
      short8 af[4];
      #pragma unroll
      for (int rt=0;rt<4;rt++)
        af[rt] = *(const short8*)&As[(rt*16+m)*128 + kt*32 + q*8];
      #pragma unroll
      for (int j=0;j<4;j++)
        #pragma unroll
        for (int rt=0;rt<4;rt++)
          acc[rt][j] = __builtin_amdgcn_mfma_f32_16x16x32_bf16(af[rt], breg[j][kt], acc[rt][j], 0,0,0);
    }
    __syncthreads();                               // all af reads done -> safe to write H
    #pragma unroll
    for (int rt=0;rt<4;rt++){
      #pragma unroll
      for (int i=0;i<4;i++){
        int lrow = rt*16 + q*4 + i;
        float rr = fsig_(acc[rt][0][i] + bv[0]);
        float zz = fsig_(acc[rt][1][i] + bv[1]);
        float hn = acc[rt][3][i] + bv[3];
        float nn = ftanh_(acc[rt][2][i] + bv[2] + (rr - 1.f)*hn);
        float hp = bf2f(As[lrow*128 + 64 + u]);    // own (lrow,u): no cross-wave hazard
        unsigned short hb = f2bf((1.f - zz)*nn + zz*hp);
        if (s < 7){
          As[lrow*128 + 64 + u] = hb;
        } else {
          int nd = idxS[lrow];
          if (nd >= 0) hOut[(size_t)nd*80 + 6 + u] = hb;
        }
      }
    }
  }
}

// ======== wgemm: B-in-registers MFMA GEMM (msg layers) =============================
template<int RTR, int KT, int CT>
__global__ __launch_bounds__(256) void wgemm(
    const unsigned short* __restrict__ A0, int w0, int ldA0,
    const unsigned short* __restrict__ A1, int w1, int ldA1,
    const unsigned short* __restrict__ Bt, int KpB,
    const float* __restrict__ bias,
    unsigned short* __restrict__ C, int ldC,
    int rows, int tiles, int act)
{
  constexpr int Kpad = KT*32;
  constexpr int NRT  = RTR/16;
  constexpr int CPT  = (RTR*Kpad/8)/256;
  __shared__ __align__(16) unsigned short As[2][RTR*Kpad];
  int t = threadIdx.x;
  int lane = t & 63, m = lane & 15, q = lane >> 4, w = t >> 6;
  int tileBase = blockIdx.y * (4*CT);
  int rtEnd = (rows + RTR - 1)/RTR;
  int tr = blockIdx.x;
  if (tr >= rtEnd) return;

  short8 breg[CT][KT]; float bv[CT]; bool val[CT]; int colr[CT];
  #pragma unroll
  for (int j=0;j<CT;j++){
    int tt = tileBase + w + 4*j;
    val[j] = (tt < tiles);
    int col = tt*16 + m;
    colr[j] = col;
    bv[j] = 0.f;
    if (val[j]){
      bv[j] = bias[col];
      #pragma unroll
      for (int kt=0;kt<KT;kt++)
        breg[j][kt] = *(const short8*)&Bt[(size_t)col*KpB + kt*32 + q*8];
    } else {
      #pragma unroll
      for (int kt=0;kt<KT;kt++) breg[j][kt] = (short8){0,0,0,0,0,0,0,0};
    }
  }

  int w01 = w0 + w1;
  uint4 r[CPT];
  auto loadRegs = [&](int trr){
    #pragma unroll
    for (int i=0;i<CPT;i++){
      int c = i*256 + t;
      int row = c / (KT*4), kc = (c - row*(KT*4))*8;
      int gr = trr*RTR + row;
      uint4 v = {0,0,0,0};
      if (gr < rows && kc < w01){
        const unsigned short* sp = (kc < w0) ? A0 + (size_t)gr*ldA0 + kc
                                             : A1 + (size_t)gr*ldA1 + (kc - w0);
        v = *(const uint4*)sp;
      }
      r[i] = v;
    }
  };
  auto dsw = [&](int p){
    #pragma unroll
    for (int i=0;i<CPT;i++){
      int c = i*256 + t;
      int row = c / (KT*4), kc = (c - row*(KT*4))*8;
      *(uint4*)&As[p][row*Kpad + kc] = r[i];
    }
  };

  loadRegs(tr);
  dsw(0);
  int p = 0;
  for (;;){
    int nxt = tr + gridDim.x;
    bool hasNext = (nxt < rtEnd);
    if (hasNext) loadRegs(nxt);
    __syncthreads();
    f32x4 acc[NRT][CT] = {};
    #pragma unroll
    for (int kt=0;kt<KT;kt++){
      short8 af[NRT];
      #pragma unroll
      for (int rt=0;rt<NRT;rt++)
        af[rt] = *(const short8*)&As[p][(rt*16+m)*Kpad + kt*32 + q*8];
      #pragma unroll
      for (int j=0;j<CT;j++)
        #pragma unroll
        for (int rt=0;rt<NRT;rt++)
          acc[rt][j] = __builtin_amdgcn_mfma_f32_16x16x32_bf16(af[rt], breg[j][kt], acc[rt][j], 0,0,0);
    }
    bool tfull = (tr*RTR + RTR <= rows);
#define EPILOG(CHK)                                                         \
    _Pragma("unroll")                                                       \
    for (int rt=0;rt<NRT;rt++){                                             \
      int rbase = tr*RTR + rt*16 + q*4;                                     \
      _Pragma("unroll")                                                     \
      for (int j=0;j<CT;j++){                                               \
        if (!val[j]) continue;                                              \
        _Pragma("unroll")                                                   \
        for (int i=0;i<4;i++){                                              \
          int grow = rbase + i;                                             \
          if (CHK && grow >= rows) continue;                                \
          float v = acc[rt][j][i] + bv[j];                                  \
          if (act == 1) v = fgelu_(v);                                      \
          else if (act == 2) v = ftanh_(v);                                 \
          C[(size_t)grow*ldC + colr[j]] = f2bf(v);                          \
        }                                                                   \
      }                                                                     \
    }
    if (tfull){ EPILOG(false) } else { EPILOG(true) }
#undef EPILOG
    if (!hasNext) break;
    dsw(p^1);
    p ^= 1; tr = nxt;
  }
}

// ======== ugemm: update-GEMM with CSR gather-max fused as an in-block phase ========
// Phase 1a: wave-per-node gather-max (padded int4 edata, lanes across cols) writes
//           agg DIRECTLY into As[row][gK..Kpad) (bf16 max = exact selection).
// Phase 1b: stage global A segments into As[row][0..gK). One barrier. Phase 2: MFMA.
// Single tile per block (grid covers all row tiles), LDS = RTR*Kpad*2 = 20 KB.
template<int RTR, int KT, int CT, int MAGG>
__global__ __launch_bounds__(256) void ugemm(
    const unsigned short* __restrict__ A0, int w0, int ldA0,
    const unsigned short* __restrict__ A1, int w1, int ldA1,
    const unsigned short* __restrict__ Bt, int KpB,
    const float* __restrict__ bias,
    unsigned short* __restrict__ C, int ldC,
    int rows, int tiles, int act,
    const int* __restrict__ off, const int* __restrict__ edata,
    const unsigned short* __restrict__ P2, int ldP, int off1)
{
  constexpr int Kpad = KT*32;
  constexpr int gK   = Kpad - MAGG;      // global-loaded K prefix
  constexpr int NRT  = RTR/16;
  constexpr int NPW  = RTR/4;            // agg nodes per wave
  __shared__ __align__(16) unsigned short As[RTR*Kpad];
  int t = threadIdx.x;
  int lane = t & 63, m = lane & 15, q = lane >> 4, w = t >> 6;
  int rb = blockIdx.x * RTR;

  short8 breg[CT][KT]; float bv[CT]; bool val[CT]; int colr[CT];
  #pragma unroll
  for (int j=0;j<CT;j++){
    int tt = w + 4*j;
    val[j] = (tt < tiles);
    int col = tt*16 + m;
    colr[j] = col;
    bv[j] = 0.f;
    if (val[j]){
      bv[j] = bias[col];
      #pragma unroll
      for (int kt=0;kt<KT;kt++)
        breg[j][kt] = *(const short8*)&Bt[(size_t)col*KpB + kt*32 + q*8];
    } else {
      #pragma unroll
      for (int kt=0;kt<KT;kt++) breg[j][kt] = (short8){0,0,0,0,0,0,0,0};
    }
  }

  const float NEG = -__builtin_inff();
  // ---- phase 1a: fused aggregate -> As agg region ----
  if (MAGG <= 128){
    int c = 2*lane;
    bool actL = c < MAGG;
    for (int i=0;i<NPW;i++){
      int lrow = w*NPW + i;
      int node = rb + lrow;
      if (node >= rows) break;           // wave-uniform
      int e0 = off[node], e1 = off[node+1];
      float f0 = NEG, f1 = NEG;
      for (int e = e0; e < e1; e += 4){
        int4 w4 = *(const int4*)&edata[e];
        if (actL){
          unsigned int u0 = *(const unsigned int*)(P2 + (size_t)(w4.x>>1)*ldP + (w4.x&1)*off1 + c);
          unsigned int u1 = *(const unsigned int*)(P2 + (size_t)(w4.y>>1)*ldP + (w4.y&1)*off1 + c);
          unsigned int u2 = *(const unsigned int*)(P2 + (size_t)(w4.z>>1)*ldP + (w4.z&1)*off1 + c);
          unsigned int u3 = *(const unsigned int*)(P2 + (size_t)(w4.w>>1)*ldP + (w4.w&1)*off1 + c);
          f0 = fmaxf(f0, fmaxf(fmaxf(__uint_as_float(u0<<16), __uint_as_float(u1<<16)),
                               fmaxf(__uint_as_float(u2<<16), __uint_as_float(u3<<16))));
          f1 = fmaxf(f1, fmaxf(fmaxf(__uint_as_float(u0&0xFFFF0000u), __uint_as_float(u1&0xFFFF0000u)),
                               fmaxf(__uint_as_float(u2&0xFFFF0000u), __uint_as_float(u3&0xFFFF0000u))));
        }
      }
      if (actL){
        unsigned int o = (__float_as_uint(f0 == NEG ? 0.f : f0) >> 16)
                       |  (__float_as_uint(f1 == NEG ? 0.f : f1) & 0xFFFF0000u);
        *(unsigned int*)&As[lrow*Kpad + gK + c] = o;
      }
    }
  } else {
    int c = 4*lane;
    bool actL = c < MAGG;
    for (int i=0;i<NPW;i++){
      int lrow = w*NPW + i;
      int node = rb + lrow;
      if (node >= rows) break;
      int e0 = off[node], e1 = off[node+1];
      float f0 = NEG, f1 = NEG, f2 = NEG, f3 = NEG;
      for (int e = e0; e < e1; e += 4){
        int4 w4 = *(const int4*)&edata[e];
        if (actL){
          uint2 u0 = *(const uint2*)(P2 + (size_t)(w4.x>>1)*ldP + (w4.x&1)*off1 + c);
          uint2 u1 = *(const uint2*)(P2 + (size_t)(w4.y>>1)*ldP + (w4.y&1)*off1 + c);
          uint2 u2 = *(const uint2*)(P2 + (size_t)(w4.z>>1)*ldP + (w4.z&1)*off1 + c);
          uint2 u3 = *(const uint2*)(P2 + (size_t)(w4.w>>1)*ldP + (w4.w&1)*off1 + c);
          f0 = fmaxf(f0, fmaxf(fmaxf(__uint_as_float(u0.x<<16), __uint_as_float(u1.x<<16)),
                               fmaxf(__uint_as_float(u2.x<<16), __uint_as_float(u3.x<<16))));
          f1 = fmaxf(f1, fmaxf(fmaxf(__uint_as_float(u0.x&0xFFFF0000u), __uint_as_float(u1.x&0xFFFF0000u)),
                               fmaxf(__uint_as_float(u2.x&0xFFFF0000u), __uint_as_float(u3.x&0xFFFF0000u))));
          f2 = fmaxf(f2, fmaxf(fmaxf(__uint_as_float(u0.y<<16), __uint_as_float(u1.y<<16)),
                               fmaxf(__uint_as_float(u2.y<<16), __uint_as_float(u3.y<<16))));
          f3 = fmaxf(f3, fmaxf(fmaxf(__uint_as_float(u0.y&0xFFFF0000u), __uint_as_float(u1.y&0xFFFF0000u)),
                               fmaxf(__uint_as_float(u2.y&0xFFFF0000u), __uint_as_float(u3.y&0xFFFF0000u))));
        }
      }
      if (actL){
        unsigned int ox = (__float_as_uint(f0 == NEG ? 0.f : f0) >> 16)
                        |  (__float_as_uint(f1 == NEG ? 0.f : f1) & 0xFFFF0000u);
        unsigned int oy = (__float_as_uint(f2 == NEG ? 0.f : f2) >> 16)
                        |  (__float_as_uint(f3 == NEG ? 0.f : f3) & 0xFFFF0000u);
        *(unsigned int*)&As[lrow*Kpad + gK + c]     = ox;
        *(unsigned int*)&As[lrow*Kpad + gK + c + 2] = oy;
      }
    }
  }
  // ---- phase 1b: stage global segments ----
  {
    constexpr int CHUNKS = RTR*gK/8;
    int w01 = w0 + w1;
    for (int j = t; j < CHUNKS; j += 256){
      int row = j / (gK/8);
      int kc = (j - row*(gK/8))*8;
      int gr = rb + row;
      uint4 v = {0,0,0,0};
      if (gr < rows && kc < w01){
        const unsigned short* sp = (kc < w0) ? A0 + (size_t)gr*ldA0 + kc
                                             : A1 + (size_t)gr*ldA1 + (kc - w0);
        v = *(const uint4*)sp;
      }
      *(uint4*)&As[row*Kpad + kc] = v;
    }
  }
  __syncthreads();
  // ---- phase 2: MFMA + epilogue ----
  f32x4 acc[NRT][CT] = {};
  #pragma unroll
  for (int kt=0;kt<KT;kt++){
    short8 af[NRT];
    #pragma unroll
    for (int rt=0;rt<NRT;rt++)
      af[rt] = *(const short8*)&As[(rt*16+m)*Kpad + kt*32 + q*8];
    #pragma unroll
    for (int j=0;j<CT;j++)
      #pragma unroll
      for (int rt=0;rt<NRT;rt++)
        acc[rt][j] = __builtin_amdgcn_mfma_f32_16x16x32_bf16(af[rt], breg[j][kt], acc[rt][j], 0,0,0);
  }
  bool tfull = (rb + RTR <= rows);
  #pragma unroll
  for (int rt=0;rt<NRT;rt++){
    int rbase = rb + rt*16 + q*4;
    #pragma unroll
    for (int j=0;j<CT;j++){
      if (!val[j]) continue;
      #pragma unroll
      for (int i=0;i<4;i++){
        int grow = rbase + i;
        if (!tfull && grow >= rows) continue;
        float v = acc[rt][j][i] + bv[j];
        if (act == 1) v = fgelu_(v);
        else if (act == 2) v = ftanh_(v);
        C[(size_t)grow*ldC + colr[j]] = f2bf(v);
      }
    }
  }
}

// ---------------- final head ----------------
__global__ void k_head(const unsigned short* __restrict__ h, const int* __restrict__ entry,
                       const float* __restrict__ W1, const float* __restrict__ b1,
                       const float* __restrict__ W2, const float* __restrict__ b2,
                       float* __restrict__ out){
  __shared__ float x[70], x1[70];
  int t = threadIdx.x;
  if (t < 70) x[t] = bf2f(h[(size_t)(*entry)*80 + t]);
  __syncthreads();
  if (t < 70){
    float s = b1[t];
    for (int i=0;i<70;i++) s += x[i]*W1[i*70 + t];
    x1[t] = fmaxf(s, 0.f);
  }
  __syncthreads();
  if (t < 640){
    float s = b2[t];
    for (int i=0;i<70;i++) s += x1[i]*W2[i*640 + t];
    out[t] = s;
  }
}

extern "C" void kernel_launch(void* const* d_in, const int* in_sizes, int n_in,
                              void* d_out, int out_size, void* d_ws, size_t ws_size,
                              hipStream_t stream) {
  const int*   tokens   = (const int*)d_in[0];
  const int*   type_idx = (const int*)d_in[1];
  const int*   esrc     = (const int*)d_in[2];
  const int*   edst     = (const int*)d_in[3];
  const int*   entry    = (const int*)d_in[4];
  const float* embed    = (const float*)d_in[5];
  const float* Wi_map   = (const float*)d_in[6];
  const float* Wh_map   = (const float*)d_in[7];
  const float* bi_map   = (const float*)d_in[8];
  const float* bh_map   = (const float*)d_in[9];
  const float* Wi_mem   = (const float*)d_in[10];
  const float* Wh_mem   = (const float*)d_in[11];
  const float* bi_mem   = (const float*)d_in[12];
  const float* bh_mem   = (const float*)d_in[13];
  const float* Wm_plain = (const float*)d_in[14];
  const float* bm_plain = (const float*)d_in[15];
  const float* Wu_plain = (const float*)d_in[16];
  const float* bu_plain = (const float*)d_in[17];
  const float* Wm_ar    = (const float*)d_in[18];
  const float* bm_ar    = (const float*)d_in[19];
  const float* Wu_ar    = (const float*)d_in[20];
  const float* bu_ar    = (const float*)d_in[21];
  const float* W1 = (const float*)d_in[22];
  const float* b1 = (const float*)d_in[23];
  const float* W2 = (const float*)d_in[24];
  const float* b2 = (const float*)d_in[25];
  float* out = (float*)d_out;

  const int N  = in_sizes[1];      // 100000
  const int TE = in_sizes[2];      // 500000
  const int E  = TE / 2;
  const int V64 = in_sizes[5];     // V*DE = 640000

  char* p = (char*)d_ws;
  auto alloc = [&](size_t bytes)->char* { char* r = p; p += (bytes + 255) & ~(size_t)255; return r; };
  unsigned short* hA  = (unsigned short*)alloc((size_t)N*80*2);
  unsigned short* hB  = (unsigned short*)alloc((size_t)N*80*2);
  unsigned short* hC  = (unsigned short*)alloc((size_t)N*80*2);
  unsigned short* P2  = (unsigned short*)alloc((size_t)N*320*2);
  int* deg    = (int*)alloc((size_t)N*4);
  int* curp   = (int*)alloc((size_t)N*4);
  int* off    = (int*)alloc((size_t)(N+8)*4);
  int* edata  = (int*)alloc((size_t)(TE + 4*N + 16)*4);            // padded CSR
  int* sbsum  = (int*)alloc(256*4);
  int* cnt    = (int*)alloc(16*4);
  int* idxcat = (int*)alloc((size_t)R2*4);
  unsigned short* BtA  = (unsigned short*)alloc(388096*2);
  float* biasA = (float*)alloc(2752*4);
  unsigned short* embB = (unsigned short*)alloc((size_t)V64*2);

  hipMemsetAsync(idxcat, 0xFF, (size_t)R2*4, stream);
  hipMemsetAsync(cnt,    0,    16*4, stream);
  hipMemsetAsync(deg,    0,    (size_t)N*4, stream);
  hipMemsetAsync(curp,   0,    (size_t)N*4, stream);

  k_prepB<<<dim3(8,18), 256, 0, stream>>>(Wm_plain, Wu_plain, Wm_ar, Wu_ar,
                                          Wi_map, Wh_map, Wi_mem, Wh_mem, BtA);
  k_prepBias<<<1, 256, 0, stream>>>(bm_plain, bu_plain, bm_ar, bu_ar,
                                    bi_map, bh_map, bi_mem, bh_mem, biasA);
  k_prepEmb<<<(V64+255)/256, 256, 0, stream>>>(embed, embB, V64);
  k_init_h<<<(N*80+255)/256, 256, 0, stream>>>(type_idx, hA, N);
  k_compact<<<(N+255)/256, 256, 0, stream>>>(type_idx, idxcat, cnt, N);

  k_count<<<(TE+255)/256, 256, 0, stream>>>(edst, deg, TE);
  int nb = (N + 2047)/2048;
  k_scan1<<<nb, 256, 0, stream>>>(deg, off, sbsum, N);
  k_scan2<<<1, 64, 0, stream>>>(sbsum, nb);
  k_scan3<<<(N+255)/256, 256, 0, stream>>>(off, sbsum, N, nb);
  k_fill<<<(TE+255)/256, 256, 0, stream>>>(esrc, edst, off, curp, edata, TE, E);
  k_pad<<<(N+255)/256, 256, 0, stream>>>(off, curp, edata, N);

  // ---- GRU: one persistent launch (8 steps internal), scatter fused ----
  kgru<<<dim3(CAPT/64, 2), 256, 0, stream>>>(
      idxcat, tokens, embB,
      BtA + 322560, BtA + 322560 + 32768,
      biasA + 2240, biasA + 2240 + 256, hA);

  // ---- 2 blocks x (3 plain MP + concat-residual AR MP); aggregate fused in upd ----
  unsigned short* cur = hA; unsigned short* f1 = hB; unsigned short* f2 = hC;
  int li = 0;
  for (int blk = 0; blk < 2; blk++){
    unsigned short* saved = cur;
    unsigned short* ins[3]  = {cur, f1, f2};
    unsigned short* outs[3] = {f1, f2, f1};
    for (int j = 0; j < 3; j++){
      unsigned short* X = ins[j]; unsigned short* Yo = outs[j];
      // msg: [N,80] @ [96->160] (both edge types fused in cols)
      wgemm<64,3,3><<<dim3(1024,1), 256, 0, stream>>>(
          X, 80, 80,  nullptr, 0, 0,
          BtA + li*15360, 96, biasA + li*160,
          P2, 160, N, 10, 0);
      // upd: [N, 80 | agg(80)] @ [160->80], aggregate fused in-block
      ugemm<64,5,2,80><<<(N+63)/64, 256, 0, stream>>>(
          X, 80, 80,  nullptr, 0, 0,
          BtA + 92160 + li*12800, 160, biasA + 960 + li*80,
          Yo, 80, N, 5, 0,
          off, edata, P2, 160, 80);
      li++;
    }
    // AR msg: [N,80|80] @ [160->320], gelu; y splits 20 col tiles into 12+8
    wgemm<64,5,3><<<dim3(512,2), 256, 0, stream>>>(
        saved, 80, 80,  f1, 80, 80,
        BtA + 168960 + blk*51200, 160, biasA + 1440 + blk*320,
        P2, 320, N, 20, 1 /*gelu*/);
    // AR upd: [N, 80|80 | agg(160)] @ [320->80], tanh, aggregate fused in-block
    ugemm<32,10,2,160><<<(N+31)/32, 256, 0, stream>>>(
        saved, 80, 80,  f1, 80, 80,
        BtA + 271360 + blk*25600, 320, biasA + 2080 + blk*80,
        f2, 80, N, 5, 2 /*tanh*/,
        off, edata, P2, 320, 160);
    unsigned short* t3 = cur; cur = f2; f2 = t3;
  }

  k_head<<<1, 640, 0, stream>>>(cur, entry, W1, b1, W2, b2, out);
}

// Round 8
// 1050.817 us; speedup vs baseline: 1.1229x; 1.1229x over previous
//
#include <hip/hip_runtime.h>
#include <math.h>

#define CAPT 20480              // per-type compacted-node capacity (actual ~16.7k)
#define R2   (2*CAPT)

typedef __attribute__((ext_vector_type(8))) short short8;
typedef __attribute__((ext_vector_type(4))) float f32x4;

// ---- fast transcendentals: v_exp_f32 / v_rcp_f32 based; err ~1e-7 << bf16 ulp ----
__device__ __forceinline__ float fexp2_(float x){ return __builtin_amdgcn_exp2f(x); }
__device__ __forceinline__ float frcp_(float x){ return __builtin_amdgcn_rcpf(x); }
__device__ __forceinline__ float ftanh_(float x){
  float ax = __builtin_fabsf(x);
  float t = fexp2_(-2.885390082f * ax);          // e^{-2|x|}
  float r = (1.f - t) * frcp_(1.f + t);
  return __builtin_copysignf(r, x);
}
__device__ __forceinline__ float fsig_(float x){
  return frcp_(1.f + fexp2_(-1.442695041f * x));
}
__device__ __forceinline__ float fgelu_(float x){
  const float c = 0.7978845608028654f;
  return 0.5f*x*(1.f + ftanh_(c*(x + 0.044715f*x*x*x)));
}
__device__ __forceinline__ unsigned short f2bf(float x){
  unsigned int u = __float_as_uint(x);
  return (unsigned short)((u + 0x7FFFu + ((u>>16)&1u)) >> 16);
}
__device__ __forceinline__ float bf2f(unsigned short v){
  return __uint_as_float(((unsigned int)v) << 16);
}

// ---------------- weight prep: transposed bf16 B arena, padded to 16-mult segments ----
// Arena layout (bf16 elems):
//  [0..6)      plain msg li:  [160][96]   off = li*15360
//  [6..12)     plain upd li:  [80][160]   off = 92160 + li*12800
//  [12..14)    ar msg blk:    [320][160]  off = 168960 + blk*51200
//  [14..16)    ar upd blk:    [80][320]   off = 271360 + blk*25600
//  [16..18)    gru typ:       [256][128]  off = 322560 + typ*32768
__global__ void k_prepB(const float* __restrict__ Wm_plain, const float* __restrict__ Wu_plain,
                        const float* __restrict__ Wm_ar, const float* __restrict__ Wu_ar,
                        const float* __restrict__ Wi_map, const float* __restrict__ Wh_map,
                        const float* __restrict__ Wi_mem, const float* __restrict__ Wh_mem,
                        unsigned short* __restrict__ BtArena){
  int id = blockIdx.y;
  int Kp, elems, off;
  if (id < 6){ Kp=96;  elems=15360; off=id*15360; }
  else if (id < 12){ Kp=160; elems=12800; off=92160+(id-6)*12800; }
  else if (id < 14){ Kp=160; elems=51200; off=168960+(id-12)*51200; }
  else if (id < 16){ Kp=320; elems=25600; off=271360+(id-14)*25600; }
  else { Kp=128; elems=32768; off=322560+(id-16)*32768; }
  for (int g = blockIdx.x*256 + threadIdx.x; g < elems; g += 8*256){
    int c = g / Kp, k = g - c*Kp;
    float val = 0.f;
    if (id < 6){
      int li = id; int t = (c >= 80); int cc = c - t*80;
      if (cc < 70 && k < 70) val = Wm_plain[((li*2+t)*70 + k)*70 + cc];
    } else if (id < 12){
      int li = id-6;
      int kk = (k < 70) ? k : ((k >= 80 && k < 150) ? 70 + (k-80) : -1);
      if (c < 70 && kk >= 0) val = Wu_plain[(li*140 + kk)*70 + c];
    } else if (id < 14){
      int blk = id-12; int t = (c >= 160); int cc = c - t*160;
      int kk = (k < 70) ? k : ((k >= 80 && k < 150) ? 70 + (k-80) : -1);
      if (cc < 140 && kk >= 0) val = Wm_ar[(((blk*2+t)*140) + kk)*140 + cc];
    } else if (id < 16){
      int blk = id-14;
      int kk = (k < 70) ? k : ((k >= 80 && k < 150) ? 70 + (k-80)
               : ((k >= 160 && k < 300) ? 140 + (k-160) : -1));
      if (c < 70 && kk >= 0) val = Wu_ar[(blk*280 + kk)*70 + c];
    } else {
      int typ = id-16;
      const float* Wi = typ ? Wi_mem : Wi_map;
      const float* Wh = typ ? Wh_mem : Wh_map;
      if (c < 192) val = (k < 64) ? Wi[c*64 + k] : Wh[c*64 + (k-64)];
      else { int cc = c-192; val = (k >= 64) ? Wh[(128+cc)*64 + (k-64)] : 0.f; }
    }
    BtArena[off + g] = f2bf(val);
  }
}

// bias arena (fp32): [0..960) plain msg [160]x6; [960..1440) plain upd [80]x6;
// [1440..2080) ar msg [320]x2; [2080..2240) ar upd [80]x2; [2240..2752) gru [256]x2
__global__ void k_prepBias(const float* __restrict__ bm_plain, const float* __restrict__ bu_plain,
                           const float* __restrict__ bm_ar, const float* __restrict__ bu_ar,
                           const float* __restrict__ bi_map, const float* __restrict__ bh_map,
                           const float* __restrict__ bi_mem, const float* __restrict__ bh_mem,
                           float* __restrict__ biasA){
  for (int g = threadIdx.x; g < 2752; g += 256){
    float val = 0.f;
    if (g < 960){ int li=g/160, c=g%160; int t=(c>=80); int cc=c-t*80;
      if (cc<70) val = bm_plain[(li*2+t)*70 + cc]; }
    else if (g < 1440){ int u=g-960; int li=u/80, c=u%80; if (c<70) val = bu_plain[li*70+c]; }
    else if (g < 2080){ int u=g-1440; int blk=u/320, c=u%320; int t=(c>=160); int cc=c-t*160;
      if (cc<140) val = bm_ar[(blk*2+t)*140 + cc]; }
    else if (g < 2240){ int u=g-2080; int blk=u/80, c=u%80; if (c<70) val = bu_ar[blk*70+c]; }
    else { int u=g-2240; int typ=u/256, c=u%256;
      const float* bi = typ ? bi_mem : bi_map; const float* bh = typ ? bh_mem : bh_map;
      val = (c < 192) ? (bi[c]+bh[c]) : bh[128 + (c-192)]; }
    biasA[g] = val;
  }
}

// ---------------- embed -> bf16 table (1.28 MB, L2-resident for the gather) ----------
__global__ void k_prepEmb(const float* __restrict__ embed, unsigned short* __restrict__ embB,
                          int total){
  int g = blockIdx.x*256 + threadIdx.x;
  if (g < total) embB[g] = f2bf(embed[g]);
}

// ---------------- init h = [one_hot(type,6) | zeros] bf16, stride 80 ----------------
__global__ void k_init_h(const int* __restrict__ type_idx, unsigned short* __restrict__ h, int N){
  int g = blockIdx.x*256 + threadIdx.x;
  if (g >= N*80) return;
  int n = g / 80, c = g - n*80;
  h[g] = (c < 6 && type_idx[n] == c) ? (unsigned short)0x3F80 : (unsigned short)0;
}

__global__ void k_compact(const int* __restrict__ type_idx, int* __restrict__ idxcat,
                          int* __restrict__ cnt, int N){
  int n = blockIdx.x*256 + threadIdx.x;
  if (n >= N) return;
  int t = type_idx[n];
  if (t == 0){ int p = atomicAdd(&cnt[0],1); if (p < CAPT) idxcat[p] = n; }
  else if (t == 5){ int p = atomicAdd(&cnt[1],1); if (p < CAPT) idxcat[CAPT+p] = n; }
}

// ---------------- CSR build, per-node edge count padded to multiple of 4 -------------
__global__ void k_count(const int* __restrict__ edst, int* __restrict__ deg, int TE){
  int i = blockIdx.x*256 + threadIdx.x;
  if (i < TE) atomicAdd(&deg[edst[i]], 1);
}
__global__ void k_scan1(const int* __restrict__ deg, int* __restrict__ off,
                        int* __restrict__ bsum, int N){
  __shared__ int sh[256];
  int t = threadIdx.x; int base = blockIdx.x*2048;
  int v[8]; int s = 0;
  for (int i=0;i<8;i++){
    int g = base + t*8 + i;
    int x = (g<N)? (((deg[g]+3)>>2)<<2) : 0;     // pad to x4
    v[i]=x; s+=x;
  }
  sh[t]=s; __syncthreads();
  for (int o=1;o<256;o<<=1){ int x = (t>=o)? sh[t-o]:0; __syncthreads(); sh[t]+=x; __syncthreads(); }
  if (t==255) bsum[blockIdx.x] = sh[255];
  int run = sh[t]-s;
  for (int i=0;i<8;i++){ int g = base + t*8 + i; if (g<N) off[g]=run; run+=v[i]; }
}
__global__ void k_scan2(int* bsum, int nb){
  if (threadIdx.x==0 && blockIdx.x==0){
    int run=0;
    for(int b=0;b<nb;b++){ int x=bsum[b]; bsum[b]=run; run+=x; }
    bsum[nb]=run;                                 // grand total (padded)
  }
}
__global__ void k_scan3(int* __restrict__ off, const int* __restrict__ bsum, int N, int nb){
  int g = blockIdx.x*256+threadIdx.x;
  if (g < N) off[g] += bsum[g>>11];
  if (g == 0) off[N] = bsum[nb];
}
__global__ void k_fill(const int* __restrict__ esrc, const int* __restrict__ edst,
                       const int* __restrict__ off, int* __restrict__ cur,
                       int* __restrict__ edata, int TE, int E){
  int i = blockIdx.x*256 + threadIdx.x;
  if (i >= TE) return;
  int d = edst[i];
  int pos = off[d] + atomicAdd(&cur[d], 1);
  edata[pos] = (esrc[i] << 1) | (i >= E ? 1 : 0);
}
// pad slots [deg, deg4) with a duplicate of the node's first edge (idempotent for max)
__global__ void k_pad(const int* __restrict__ off, const int* __restrict__ cur,
                      int* __restrict__ edata, int N){
  int n = blockIdx.x*256 + threadIdx.x;
  if (n >= N) return;
  int d = cur[n];
  if (d == 0) return;
  int d4 = ((d+3)>>2)<<2;
  int base = off[n];
  int first = edata[base];
  for (int i = d; i < d4; i++) edata[base+i] = first;
}

// ======== kgru: persistent GRU — all 8 steps in one launch, H lives in LDS =========
__global__ __launch_bounds__(256) void kgru(
    const int* __restrict__ idxcat, const int* __restrict__ tokens,
    const unsigned short* __restrict__ embB,
    const unsigned short* __restrict__ Bt, const unsigned short* __restrict__ Bt2,
    const float* __restrict__ bias, const float* __restrict__ bias2,
    unsigned short* __restrict__ hOut)
{
  __shared__ __align__(16) unsigned short As[64*128];
  __shared__ int tokS[64*8];
  __shared__ int idxS[64];
  int rb = blockIdx.y * CAPT + blockIdx.x * 64;
  if (idxcat[rb] < 0) return;                      // all-pad block
  int t = threadIdx.x;
  int lane = t & 63, m = lane & 15, q = lane >> 4, w = t >> 6;
  const unsigned short* Bsel = blockIdx.y ? Bt2 : Bt;
  const float* bsel = blockIdx.y ? bias2 : bias;
  short8 breg[4][4]; float bv[4];
  #pragma unroll
  for (int j=0;j<4;j++){
    int col = (w + 4*j)*16 + m;
    bv[j] = bsel[col];
    #pragma unroll
    for (int kt=0;kt<4;kt++)
      breg[j][kt] = *(const short8*)&Bsel[(size_t)col*128 + kt*32 + q*8];
  }
  if (t < 64) idxS[t] = idxcat[rb + t];
  for (int j = t; j < 512; j += 256){
    int nd = idxcat[rb + (j>>3)]; if (nd < 0) nd = 0;
    tokS[j] = tokens[nd*8 + (j & 7)];
  }
  for (int j = t; j < 2048; j += 256){             // zero H region
    int row = j >> 5, uu = (j & 31)*2;
    *(unsigned int*)&As[row*128 + 64 + uu] = 0;
  }
  __syncthreads();
  int u = w*16 + m;
  for (int s = 0; s < 8; s++){
    uint4 xr[2];
    #pragma unroll
    for (int i=0;i<2;i++){
      int j = t + i*256;
      int row = j >> 3, ch = j & 7;
      int tok = tokS[row*8 + s];
      xr[i] = *(const uint4*)&embB[(size_t)tok*64 + ch*8];
    }
    __syncthreads();                               // prior step's LDS reads done
    #pragma unroll
    for (int i=0;i<2;i++){
      int j = t + i*256;
      int row = j >> 3, ch = j & 7;
      *(uint4*)&As[row*128 + ch*8] = xr[i];
    }
    __syncthreads();                               // X_s + H_s ready
    f32x4 acc[4][4] = {};
    #pragma unroll
    for (int kt=0;kt<4;kt++){
      short8 af[4];
      #pragma unroll
      for (int rt=0;rt<4;rt++)
        af[rt] = *(const short8*)&As[(rt*16+m)*128 + kt*32 + q*8];
      #pragma unroll
      for (int j=0;j<4;j++)
        #pragma unroll
        for (int rt=0;rt<4;rt++)
          acc[rt][j] = __builtin_amdgcn_mfma_f32_16x16x32_bf16(af[rt], breg[j][kt], acc[rt][j], 0,0,0);
    }
    __syncthreads();                               // all af reads done -> safe to write H
    #pragma unroll
    for (int rt=0;rt<4;rt++){
      #pragma unroll
      for (int i=0;i<4;i++){
        int lrow = rt*16 + q*4 + i;
        float rr = fsig_(acc[rt][0][i] + bv[0]);
        float zz = fsig_(acc[rt][1][i] + bv[1]);
        float hn = acc[rt][3][i] + bv[3];
        float nn = ftanh_(acc[rt][2][i] + bv[2] + (rr - 1.f)*hn);
        float hp = bf2f(As[lrow*128 + 64 + u]);    // own (lrow,u): no cross-wave hazard
        unsigned short hb = f2bf((1.f - zz)*nn + zz*hp);
        if (s < 7){
          As[lrow*128 + 64 + u] = hb;
        } else {
          int nd = idxS[lrow];
          if (nd >= 0) hOut[(size_t)nd*80 + 6 + u] = hb;
        }
      }
    }
  }
}

// ======== wgemm: B-in-registers MFMA GEMM, up to 3 concatenated A segments =========
template<int RTR, int KT, int CT>
__global__ __launch_bounds__(256) void wgemm(
    const unsigned short* __restrict__ A0, int w0, int ldA0,
    const unsigned short* __restrict__ A1, int w1, int ldA1,
    const unsigned short* __restrict__ A2, int w2, int ldA2,
    const unsigned short* __restrict__ Bt, int KpB,
    const float* __restrict__ bias,
    unsigned short* __restrict__ C, int ldC,
    int rows, int tiles, int act)
{
  constexpr int Kpad = KT*32;
  constexpr int NRT  = RTR/16;
  constexpr int CPT  = (RTR*Kpad/8)/256;
  __shared__ __align__(16) unsigned short As[2][RTR*Kpad];
  int t = threadIdx.x;
  int lane = t & 63, m = lane & 15, q = lane >> 4, w = t >> 6;
  int tileBase = blockIdx.y * (4*CT);
  int rtEnd = (rows + RTR - 1)/RTR;
  int tr = blockIdx.x;
  if (tr >= rtEnd) return;

  short8 breg[CT][KT]; float bv[CT]; bool val[CT]; int colr[CT];
  #pragma unroll
  for (int j=0;j<CT;j++){
    int tt = tileBase + w + 4*j;
    val[j] = (tt < tiles);
    int col = tt*16 + m;
    colr[j] = col;
    bv[j] = 0.f;
    if (val[j]){
      bv[j] = bias[col];
      #pragma unroll
      for (int kt=0;kt<KT;kt++)
        breg[j][kt] = *(const short8*)&Bt[(size_t)col*KpB + kt*32 + q*8];
    } else {
      #pragma unroll
      for (int kt=0;kt<KT;kt++) breg[j][kt] = (short8){0,0,0,0,0,0,0,0};
    }
  }

  int w01 = w0 + w1, w012 = w0 + w1 + w2;
  uint4 r[CPT];
  auto loadRegs = [&](int trr){
    #pragma unroll
    for (int i=0;i<CPT;i++){
      int c = i*256 + t;
      int row = c / (KT*4), kc = (c - row*(KT*4))*8;
      int gr = trr*RTR + row;
      uint4 v = {0,0,0,0};
      if (gr < rows && kc < w012){
        const unsigned short* sp;
        if (kc < w0)       sp = A0 + (size_t)gr*ldA0 + kc;
        else if (kc < w01) sp = A1 + (size_t)gr*ldA1 + (kc - w0);
        else               sp = A2 + (size_t)gr*ldA2 + (kc - w01);
        v = *(const uint4*)sp;
      }
      r[i] = v;
    }
  };
  auto dsw = [&](int p){
    #pragma unroll
    for (int i=0;i<CPT;i++){
      int c = i*256 + t;
      int row = c / (KT*4), kc = (c - row*(KT*4))*8;
      *(uint4*)&As[p][row*Kpad + kc] = r[i];
    }
  };

  loadRegs(tr);
  dsw(0);
  int p = 0;
  for (;;){
    int nxt = tr + gridDim.x;
    bool hasNext = (nxt < rtEnd);
    if (hasNext) loadRegs(nxt);
    __syncthreads();
    f32x4 acc[NRT][CT] = {};
    #pragma unroll
    for (int kt=0;kt<KT;kt++){
      short8 af[NRT];
      #pragma unroll
      for (int rt=0;rt<NRT;rt++)
        af[rt] = *(const short8*)&As[p][(rt*16+m)*Kpad + kt*32 + q*8];
      #pragma unroll
      for (int j=0;j<CT;j++)
        #pragma unroll
        for (int rt=0;rt<NRT;rt++)
          acc[rt][j] = __builtin_amdgcn_mfma_f32_16x16x32_bf16(af[rt], breg[j][kt], acc[rt][j], 0,0,0);
    }
    bool tfull = (tr*RTR + RTR <= rows);
#define EPILOG(CHK)                                                         \
    _Pragma("unroll")                                                       \
    for (int rt=0;rt<NRT;rt++){                                             \
      int rbase = tr*RTR + rt*16 + q*4;                                     \
      _Pragma("unroll")                                                     \
      for (int j=0;j<CT;j++){                                               \
        if (!val[j]) continue;                                              \
        _Pragma("unroll")                                                   \
        for (int i=0;i<4;i++){                                              \
          int grow = rbase + i;                                             \
          if (CHK && grow >= rows) continue;                                \
          float v = acc[rt][j][i] + bv[j];                                  \
          if (act == 1) v = fgelu_(v);                                      \
          else if (act == 2) v = ftanh_(v);                                 \
          C[(size_t)grow*ldC + colr[j]] = f2bf(v);                          \
        }                                                                   \
      }                                                                     \
    }
    if (tfull){ EPILOG(false) } else { EPILOG(true) }
#undef EPILOG
    if (!hasNext) break;
    dsw(p^1);
    p ^= 1; tr = nxt;
  }
}

// ---------------- CSR gather + segment max; padded int4 edata; WPN waves per node ----
// Each wave covers 80 cols (40 lanes x uint). WPN=1: M=80, 4 nodes/block.
// WPN=2: M=160, 2 nodes/block, wave (w&1) covers cols [(w&1)*80, +80).
__global__ __launch_bounds__(256) void k_aggregate(
    const int* __restrict__ off, const int* __restrict__ edata,
    const unsigned short* __restrict__ P2, int ldP, int off1,
    unsigned short* __restrict__ agg, int M, int N, int WPN)
{
  int t = threadIdx.x;
  int lane = t & 63, w = t >> 6;
  int node, c;
  if (WPN == 1){
    node = blockIdx.x*4 + w;
    c = 2*lane;
  } else {
    node = blockIdx.x*2 + (w >> 1);
    c = (w & 1)*80 + 2*lane;
  }
  if (node >= N || lane >= 40) return;
  int e0 = off[node], e1 = off[node+1];
  const float NEG = -__builtin_inff();
  float f0 = NEG, f1 = NEG;
  for (int e = e0; e < e1; e += 4){
    int4 w4 = *(const int4*)&edata[e];
    unsigned int u0 = *(const unsigned int*)(P2 + (size_t)(w4.x>>1)*ldP + (w4.x&1)*off1 + c);
    unsigned int u1 = *(const unsigned int*)(P2 + (size_t)(w4.y>>1)*ldP + (w4.y&1)*off1 + c);
    unsigned int u2 = *(const unsigned int*)(P2 + (size_t)(w4.z>>1)*ldP + (w4.z&1)*off1 + c);
    unsigned int u3 = *(const unsigned int*)(P2 + (size_t)(w4.w>>1)*ldP + (w4.w&1)*off1 + c);
    f0 = fmaxf(f0, fmaxf(fmaxf(__uint_as_float(u0<<16), __uint_as_float(u1<<16)),
                         fmaxf(__uint_as_float(u2<<16), __uint_as_float(u3<<16))));
    f1 = fmaxf(f1, fmaxf(fmaxf(__uint_as_float(u0&0xFFFF0000u), __uint_as_float(u1&0xFFFF0000u)),
                         fmaxf(__uint_as_float(u2&0xFFFF0000u), __uint_as_float(u3&0xFFFF0000u))));
  }
  unsigned int o = (__float_as_uint(f0 == NEG ? 0.f : f0) >> 16)
                 |  (__float_as_uint(f1 == NEG ? 0.f : f1) & 0xFFFF0000u);
  *(unsigned int*)(agg + (size_t)node*M + c) = o;
}

// ---------------- final head ----------------
__global__ void k_head(const unsigned short* __restrict__ h, const int* __restrict__ entry,
                       const float* __restrict__ W1, const float* __restrict__ b1,
                       const float* __restrict__ W2, const float* __restrict__ b2,
                       float* __restrict__ out){
  __shared__ float x[70], x1[70];
  int t = threadIdx.x;
  if (t < 70) x[t] = bf2f(h[(size_t)(*entry)*80 + t]);
  __syncthreads();
  if (t < 70){
    float s = b1[t];
    for (int i=0;i<70;i++) s += x[i]*W1[i*70 + t];
    x1[t] = fmaxf(s, 0.f);
  }
  __syncthreads();
  if (t < 640){
    float s = b2[t];
    for (int i=0;i<70;i++) s += x1[i]*W2[i*640 + t];
    out[t] = s;
  }
}

extern "C" void kernel_launch(void* const* d_in, const int* in_sizes, int n_in,
                              void* d_out, int out_size, void* d_ws, size_t ws_size,
                              hipStream_t stream) {
  const int*   tokens   = (const int*)d_in[0];
  const int*   type_idx = (const int*)d_in[1];
  const int*   esrc     = (const int*)d_in[2];
  const int*   edst     = (const int*)d_in[3];
  const int*   entry    = (const int*)d_in[4];
  const float* embed    = (const float*)d_in[5];
  const float* Wi_map   = (const float*)d_in[6];
  const float* Wh_map   = (const float*)d_in[7];
  const float* bi_map   = (const float*)d_in[8];
  const float* bh_map   = (const float*)d_in[9];
  const float* Wi_mem   = (const float*)d_in[10];
  const float* Wh_mem   = (const float*)d_in[11];
  const float* bi_mem   = (const float*)d_in[12];
  const float* bh_mem   = (const float*)d_in[13];
  const float* Wm_plain = (const float*)d_in[14];
  const float* bm_plain = (const float*)d_in[15];
  const float* Wu_plain = (const float*)d_in[16];
  const float* bu_plain = (const float*)d_in[17];
  const float* Wm_ar    = (const float*)d_in[18];
  const float* bm_ar    = (const float*)d_in[19];
  const float* Wu_ar    = (const float*)d_in[20];
  const float* bu_ar    = (const float*)d_in[21];
  const float* W1 = (const float*)d_in[22];
  const float* b1 = (const float*)d_in[23];
  const float* W2 = (const float*)d_in[24];
  const float* b2 = (const float*)d_in[25];
  float* out = (float*)d_out;

  const int N  = in_sizes[1];      // 100000
  const int TE = in_sizes[2];      // 500000
  const int E  = TE / 2;
  const int V64 = in_sizes[5];     // V*DE = 640000

  char* p = (char*)d_ws;
  auto alloc = [&](size_t bytes)->char* { char* r = p; p += (bytes + 255) & ~(size_t)255; return r; };
  unsigned short* hA  = (unsigned short*)alloc((size_t)N*80*2);
  unsigned short* hB  = (unsigned short*)alloc((size_t)N*80*2);
  unsigned short* hC  = (unsigned short*)alloc((size_t)N*80*2);
  unsigned short* P2  = (unsigned short*)alloc((size_t)N*320*2);
  unsigned short* agg = (unsigned short*)alloc((size_t)N*160*2);
  int* deg    = (int*)alloc((size_t)N*4);
  int* curp   = (int*)alloc((size_t)N*4);
  int* off    = (int*)alloc((size_t)(N+8)*4);
  int* edata  = (int*)alloc((size_t)(TE + 4*N + 16)*4);            // padded CSR
  int* sbsum  = (int*)alloc(256*4);
  int* cnt    = (int*)alloc(16*4);
  int* idxcat = (int*)alloc((size_t)R2*4);
  unsigned short* BtA  = (unsigned short*)alloc(388096*2);
  float* biasA = (float*)alloc(2752*4);
  unsigned short* embB = (unsigned short*)alloc((size_t)V64*2);

  hipMemsetAsync(idxcat, 0xFF, (size_t)R2*4, stream);
  hipMemsetAsync(cnt,    0,    16*4, stream);
  hipMemsetAsync(deg,    0,    (size_t)N*4, stream);
  hipMemsetAsync(curp,   0,    (size_t)N*4, stream);

  k_prepB<<<dim3(8,18), 256, 0, stream>>>(Wm_plain, Wu_plain, Wm_ar, Wu_ar,
                                          Wi_map, Wh_map, Wi_mem, Wh_mem, BtA);
  k_prepBias<<<1, 256, 0, stream>>>(bm_plain, bu_plain, bm_ar, bu_ar,
                                    bi_map, bh_map, bi_mem, bh_mem, biasA);
  k_prepEmb<<<(V64+255)/256, 256, 0, stream>>>(embed, embB, V64);
  k_init_h<<<(N*80+255)/256, 256, 0, stream>>>(type_idx, hA, N);
  k_compact<<<(N+255)/256, 256, 0, stream>>>(type_idx, idxcat, cnt, N);

  k_count<<<(TE+255)/256, 256, 0, stream>>>(edst, deg, TE);
  int nb = (N + 2047)/2048;
  k_scan1<<<nb, 256, 0, stream>>>(deg, off, sbsum, N);
  k_scan2<<<1, 64, 0, stream>>>(sbsum, nb);
  k_scan3<<<(N+255)/256, 256, 0, stream>>>(off, sbsum, N, nb);
  k_fill<<<(TE+255)/256, 256, 0, stream>>>(esrc, edst, off, curp, edata, TE, E);
  k_pad<<<(N+255)/256, 256, 0, stream>>>(off, curp, edata, N);

  // ---- GRU: one persistent launch (8 steps internal), gather+scatter fused ----
  kgru<<<dim3(CAPT/64, 2), 256, 0, stream>>>(
      idxcat, tokens, embB,
      BtA + 322560, BtA + 322560 + 32768,
      biasA + 2240, biasA + 2240 + 256, hA);

  // ---- 2 blocks x (3 plain MP + concat-residual AR MP) ----
  unsigned short* cur = hA; unsigned short* f1 = hB; unsigned short* f2 = hC;
  int li = 0;
  for (int blk = 0; blk < 2; blk++){
    unsigned short* saved = cur;
    unsigned short* ins[3]  = {cur, f1, f2};
    unsigned short* outs[3] = {f1, f2, f1};
    for (int j = 0; j < 3; j++){
      unsigned short* X = ins[j]; unsigned short* Yo = outs[j];
      // msg: [N,80] @ [96->160] (both edge types fused in cols)
      wgemm<64,3,3><<<dim3(1024,1), 256, 0, stream>>>(
          X, 80, 80,  nullptr, 0, 0,  nullptr, 0, 0,
          BtA + li*15360, 96, biasA + li*160,
          P2, 160, N, 10, 0);
      k_aggregate<<<(N+3)/4, 256, 0, stream>>>(off, edata, P2, 160, 80, agg, 80, N, 1);
      // upd: [N,80|80] @ [160->80]
      wgemm<64,5,2><<<dim3(1024,1), 256, 0, stream>>>(
          X, 80, 80,  agg, 80, 80,  nullptr, 0, 0,
          BtA + 92160 + li*12800, 160, biasA + 960 + li*80,
          Yo, 80, N, 5, 0);
      li++;
    }
    // AR msg: [N,80|80] @ [160->320], gelu; y splits 20 col tiles into 12+8
    wgemm<64,5,3><<<dim3(512,2), 256, 0, stream>>>(
        saved, 80, 80,  f1, 80, 80,  nullptr, 0, 0,
        BtA + 168960 + blk*51200, 160, biasA + 1440 + blk*320,
        P2, 320, N, 20, 1 /*gelu*/);
    k_aggregate<<<(N+1)/2, 256, 0, stream>>>(off, edata, P2, 320, 160, agg, 160, N, 2);
    // AR upd: [N,80|80|160] @ [320->80], tanh; 32-row tiles (K=320 LDS)
    wgemm<32,10,2><<<dim3(1024,1), 256, 0, stream>>>(
        saved, 80, 80,  f1, 80, 80,  agg, 160, 160,
        BtA + 271360 + blk*25600, 320, biasA + 2080 + blk*80,
        f2, 80, N, 5, 2 /*tanh*/);
    unsigned short* t3 = cur; cur = f2; f2 = t3;
  }

  k_head<<<1, 640, 0, stream>>>(cur, entry, W1, b1, W2, b2, out);
}

// Round 9
// 1008.052 us; speedup vs baseline: 1.1705x; 1.0424x over previous
//
#include <hip/hip_runtime.h>
#include <math.h>

#define CAPT 20480              // per-type compacted-node capacity (actual ~16.7k)
#define R2   (2*CAPT)
#define GLD  136                // kgru LDS row stride (ushorts): breaks pow2 banking

typedef __attribute__((ext_vector_type(8))) short short8;
typedef __attribute__((ext_vector_type(4))) float f32x4;

// ---- fast transcendentals: v_exp_f32 / v_rcp_f32 based; err ~1e-7 << bf16 ulp ----
__device__ __forceinline__ float fexp2_(float x){ return __builtin_amdgcn_exp2f(x); }
__device__ __forceinline__ float frcp_(float x){ return __builtin_amdgcn_rcpf(x); }
__device__ __forceinline__ float ftanh_(float x){
  float ax = __builtin_fabsf(x);
  float t = fexp2_(-2.885390082f * ax);          // e^{-2|x|}
  float r = (1.f - t) * frcp_(1.f + t);
  return __builtin_copysignf(r, x);
}
__device__ __forceinline__ float fsig_(float x){
  return frcp_(1.f + fexp2_(-1.442695041f * x));
}
__device__ __forceinline__ float fgelu_(float x){
  const float c = 0.7978845608028654f;
  return 0.5f*x*(1.f + ftanh_(c*(x + 0.044715f*x*x*x)));
}
__device__ __forceinline__ unsigned short f2bf(float x){
  unsigned int u = __float_as_uint(x);
  return (unsigned short)((u + 0x7FFFu + ((u>>16)&1u)) >> 16);
}
__device__ __forceinline__ float bf2f(unsigned short v){
  return __uint_as_float(((unsigned int)v) << 16);
}

// ---------------- weight prep: transposed bf16 B arena, padded to 16-mult segments ----
// Arena layout (bf16 elems):
//  [0..6)      plain msg li:  [160][96]   off = li*15360
//  [6..12)     plain upd li:  [80][160]   off = 92160 + li*12800
//  [12..14)    ar msg blk:    [320][160]  off = 168960 + blk*51200
//  [14..16)    ar upd blk:    [80][320]   off = 271360 + blk*25600
//  [16..18)    gru typ:       [256][128]  off = 322560 + typ*32768
__global__ void k_prepB(const float* __restrict__ Wm_plain, const float* __restrict__ Wu_plain,
                        const float* __restrict__ Wm_ar, const float* __restrict__ Wu_ar,
                        const float* __restrict__ Wi_map, const float* __restrict__ Wh_map,
                        const float* __restrict__ Wi_mem, const float* __restrict__ Wh_mem,
                        unsigned short* __restrict__ BtArena){
  int id = blockIdx.y;
  int Kp, elems, off;
  if (id < 6){ Kp=96;  elems=15360; off=id*15360; }
  else if (id < 12){ Kp=160; elems=12800; off=92160+(id-6)*12800; }
  else if (id < 14){ Kp=160; elems=51200; off=168960+(id-12)*51200; }
  else if (id < 16){ Kp=320; elems=25600; off=271360+(id-14)*25600; }
  else { Kp=128; elems=32768; off=322560+(id-16)*32768; }
  for (int g = blockIdx.x*256 + threadIdx.x; g < elems; g += 8*256){
    int c = g / Kp, k = g - c*Kp;
    float val = 0.f;
    if (id < 6){
      int li = id; int t = (c >= 80); int cc = c - t*80;
      if (cc < 70 && k < 70) val = Wm_plain[((li*2+t)*70 + k)*70 + cc];
    } else if (id < 12){
      int li = id-6;
      int kk = (k < 70) ? k : ((k >= 80 && k < 150) ? 70 + (k-80) : -1);
      if (c < 70 && kk >= 0) val = Wu_plain[(li*140 + kk)*70 + c];
    } else if (id < 14){
      int blk = id-12; int t = (c >= 160); int cc = c - t*160;
      int kk = (k < 70) ? k : ((k >= 80 && k < 150) ? 70 + (k-80) : -1);
      if (cc < 140 && kk >= 0) val = Wm_ar[(((blk*2+t)*140) + kk)*140 + cc];
    } else if (id < 16){
      int blk = id-14;
      int kk = (k < 70) ? k : ((k >= 80 && k < 150) ? 70 + (k-80)
               : ((k >= 160 && k < 300) ? 140 + (k-160) : -1));
      if (c < 70 && kk >= 0) val = Wu_ar[(blk*280 + kk)*70 + c];
    } else {
      int typ = id-16;
      const float* Wi = typ ? Wi_mem : Wi_map;
      const float* Wh = typ ? Wh_mem : Wh_map;
      if (c < 192) val = (k < 64) ? Wi[c*64 + k] : Wh[c*64 + (k-64)];
      else { int cc = c-192; val = (k >= 64) ? Wh[(128+cc)*64 + (k-64)] : 0.f; }
    }
    BtArena[off + g] = f2bf(val);
  }
}

// bias arena (fp32): [0..960) plain msg [160]x6; [960..1440) plain upd [80]x6;
// [1440..2080) ar msg [320]x2; [2080..2240) ar upd [80]x2; [2240..2752) gru [256]x2
__global__ void k_prepBias(const float* __restrict__ bm_plain, const float* __restrict__ bu_plain,
                           const float* __restrict__ bm_ar, const float* __restrict__ bu_ar,
                           const float* __restrict__ bi_map, const float* __restrict__ bh_map,
                           const float* __restrict__ bi_mem, const float* __restrict__ bh_mem,
                           float* __restrict__ biasA){
  for (int g = threadIdx.x; g < 2752; g += 256){
    float val = 0.f;
    if (g < 960){ int li=g/160, c=g%160; int t=(c>=80); int cc=c-t*80;
      if (cc<70) val = bm_plain[(li*2+t)*70 + cc]; }
    else if (g < 1440){ int u=g-960; int li=u/80, c=u%80; if (c<70) val = bu_plain[li*70+c]; }
    else if (g < 2080){ int u=g-1440; int blk=u/320, c=u%320; int t=(c>=160); int cc=c-t*160;
      if (cc<140) val = bm_ar[(blk*2+t)*140 + cc]; }
    else if (g < 2240){ int u=g-2080; int blk=u/80, c=u%80; if (c<70) val = bu_ar[blk*70+c]; }
    else { int u=g-2240; int typ=u/256, c=u%256;
      const float* bi = typ ? bi_mem : bi_map; const float* bh = typ ? bh_mem : bh_map;
      val = (c < 192) ? (bi[c]+bh[c]) : bh[128 + (c-192)]; }
    biasA[g] = val;
  }
}

// ---------------- embed -> bf16 table (1.28 MB, L2-resident for the gather) ----------
__global__ void k_prepEmb(const float* __restrict__ embed, unsigned short* __restrict__ embB,
                          int total){
  int g = blockIdx.x*256 + threadIdx.x;
  if (g < total) embB[g] = f2bf(embed[g]);
}

// ---------------- init h = [one_hot(type,6) | zeros] bf16, stride 80 ----------------
__global__ void k_init_h(const int* __restrict__ type_idx, unsigned short* __restrict__ h, int N){
  int g = blockIdx.x*256 + threadIdx.x;
  if (g >= N*80) return;
  int n = g / 80, c = g - n*80;
  h[g] = (c < 6 && type_idx[n] == c) ? (unsigned short)0x3F80 : (unsigned short)0;
}

__global__ void k_compact(const int* __restrict__ type_idx, int* __restrict__ idxcat,
                          int* __restrict__ cnt, int N){
  int n = blockIdx.x*256 + threadIdx.x;
  if (n >= N) return;
  int t = type_idx[n];
  if (t == 0){ int p = atomicAdd(&cnt[0],1); if (p < CAPT) idxcat[p] = n; }
  else if (t == 5){ int p = atomicAdd(&cnt[1],1); if (p < CAPT) idxcat[CAPT+p] = n; }
}

// ---------------- CSR build, per-node edge count padded to multiple of 4 -------------
__global__ void k_count(const int* __restrict__ edst, int* __restrict__ deg, int TE){
  int i = blockIdx.x*256 + threadIdx.x;
  if (i < TE) atomicAdd(&deg[edst[i]], 1);
}
__global__ void k_scan1(const int* __restrict__ deg, int* __restrict__ off,
                        int* __restrict__ bsum, int N){
  __shared__ int sh[256];
  int t = threadIdx.x; int base = blockIdx.x*2048;
  int v[8]; int s = 0;
  for (int i=0;i<8;i++){
    int g = base + t*8 + i;
    int x = (g<N)? (((deg[g]+3)>>2)<<2) : 0;     // pad to x4
    v[i]=x; s+=x;
  }
  sh[t]=s; __syncthreads();
  for (int o=1;o<256;o<<=1){ int x = (t>=o)? sh[t-o]:0; __syncthreads(); sh[t]+=x; __syncthreads(); }
  if (t==255) bsum[blockIdx.x] = sh[255];
  int run = sh[t]-s;
  for (int i=0;i<8;i++){ int g = base + t*8 + i; if (g<N) off[g]=run; run+=v[i]; }
}
__global__ void k_scan2(int* bsum, int nb){
  if (threadIdx.x==0 && blockIdx.x==0){
    int run=0;
    for(int b=0;b<nb;b++){ int x=bsum[b]; bsum[b]=run; run+=x; }
    bsum[nb]=run;                                 // grand total (padded)
  }
}
__global__ void k_scan3(int* __restrict__ off, const int* __restrict__ bsum, int N, int nb){
  int g = blockIdx.x*256+threadIdx.x;
  if (g < N) off[g] += bsum[g>>11];
  if (g == 0) off[N] = bsum[nb];
}
__global__ void k_fill(const int* __restrict__ esrc, const int* __restrict__ edst,
                       const int* __restrict__ off, int* __restrict__ cur,
                       int* __restrict__ edata, int TE, int E){
  int i = blockIdx.x*256 + threadIdx.x;
  if (i >= TE) return;
  int d = edst[i];
  int pos = off[d] + atomicAdd(&cur[d], 1);
  edata[pos] = (esrc[i] << 1) | (i >= E ? 1 : 0);
}
// pad slots [deg, deg4) with a duplicate of the node's first edge (idempotent for max)
__global__ void k_pad(const int* __restrict__ off, const int* __restrict__ cur,
                      int* __restrict__ edata, int N){
  int n = blockIdx.x*256 + threadIdx.x;
  if (n >= N) return;
  int d = cur[n];
  if (d == 0) return;
  int d4 = ((d+3)>>2)<<2;
  int base = off[n];
  int first = edata[base];
  for (int i = d; i < d4; i++) edata[base+i] = first;
}

// ======== kgru v2: persistent GRU — padded LDS stride, double buffer, 1 barrier/step
// Block = 64 rows of compacted region blockIdx.y. As[p] rows [x_s | H_s], stride GLD.
// h' kept in registers (bf16-rounded each step -> numerics identical); next step's
// H and X are written into buf p^1 while buf p is being consumed.
__global__ __launch_bounds__(256) void kgru(
    const int* __restrict__ idxcat, const int* __restrict__ tokens,
    const unsigned short* __restrict__ embB,
    const unsigned short* __restrict__ Bt, const unsigned short* __restrict__ Bt2,
    const float* __restrict__ bias, const float* __restrict__ bias2,
    unsigned short* __restrict__ hOut)
{
  __shared__ __align__(16) unsigned short As[2][64*GLD];
  __shared__ int tokS[64*8];
  __shared__ int idxS[64];
  int rb = blockIdx.y * CAPT + blockIdx.x * 64;
  if (idxcat[rb] < 0) return;                      // all-pad block
  int t = threadIdx.x;
  int lane = t & 63, m = lane & 15, q = lane >> 4, w = t >> 6;
  const unsigned short* Bsel = blockIdx.y ? Bt2 : Bt;
  const float* bsel = blockIdx.y ? bias2 : bias;
  short8 breg[4][4]; float bv[4];
  #pragma unroll
  for (int j=0;j<4;j++){
    int col = (w + 4*j)*16 + m;
    bv[j] = bsel[col];
    #pragma unroll
    for (int kt=0;kt<4;kt++)
      breg[j][kt] = *(const short8*)&Bsel[(size_t)col*128 + kt*32 + q*8];
  }
  if (t < 64) idxS[t] = idxcat[rb + t];
  for (int j = t; j < 512; j += 256){
    int nd = idxcat[rb + (j>>3)]; if (nd < 0) nd = 0;
    tokS[j] = tokens[nd*8 + (j & 7)];
  }
  __syncthreads();                                 // tokS ready
  // stage X(0) + zero H(0) into buf 0
  for (int j = t; j < 512; j += 256){
    int row = j >> 3, ch = j & 7;
    *(uint4*)&As[0][row*GLD + ch*8] = *(const uint4*)&embB[(size_t)tokS[row*8]*64 + ch*8];
  }
  for (int j = t; j < 2048; j += 256){
    int row = j >> 5, k2 = (j & 31)*2;
    *(unsigned int*)&As[0][row*GLD + 64 + k2] = 0;
  }
  __syncthreads();
  unsigned short hreg[4][4];
  #pragma unroll
  for (int rt=0;rt<4;rt++)
    #pragma unroll
    for (int i=0;i<4;i++) hreg[rt][i] = 0;
  int u = w*16 + m;
  int p = 0;
  for (int s = 0; s < 8; s++){
    uint4 xr[2];
    if (s < 7){                                    // prefetch X(s+1) early (global)
      #pragma unroll
      for (int i=0;i<2;i++){
        int j = t + i*256;
        int row = j >> 3, ch = j & 7;
        xr[i] = *(const uint4*)&embB[(size_t)tokS[row*8 + s + 1]*64 + ch*8];
      }
    }
    f32x4 acc[4][4] = {};
    #pragma unroll
    for (int kt=0;kt<4;kt++){
      short8 af[4];
      #pragma unroll
      for (int rt=0;rt<4;rt++)
        af[rt] = *(const short8*)&As[p][(rt*16+m)*GLD + kt*32 + q*8];
      #pragma unroll
      for (int j=0;j<4;j++)
        #pragma unroll
        for (int rt=0;rt<4;rt++)
          acc[rt][j] = __builtin_amdgcn_mfma_f32_16x16x32_bf16(af[rt], breg[j][kt], acc[rt][j], 0,0,0);
    }
    #pragma unroll
    for (int rt=0;rt<4;rt++){
      #pragma unroll
      for (int i=0;i<4;i++){
        float rr = fsig_(acc[rt][0][i] + bv[0]);
        float zz = fsig_(acc[rt][1][i] + bv[1]);
        float hn = acc[rt][3][i] + bv[3];
        float nn = ftanh_(acc[rt][2][i] + bv[2] + (rr - 1.f)*hn);
        float hp = bf2f(hreg[rt][i]);
        hreg[rt][i] = f2bf((1.f - zz)*nn + zz*hp);
      }
    }
    if (s < 7){
      // write H(s+1) + X(s+1) into buf p^1 (its readers all finished pre-barrier)
      #pragma unroll
      for (int rt=0;rt<4;rt++)
        #pragma unroll
        for (int i=0;i<4;i++)
          As[p^1][(rt*16 + q*4 + i)*GLD + 64 + u] = hreg[rt][i];
      #pragma unroll
      for (int i=0;i<2;i++){
        int j = t + i*256;
        int row = j >> 3, ch = j & 7;
        *(uint4*)&As[p^1][row*GLD + ch*8] = xr[i];
      }
      __syncthreads();
      p ^= 1;
    } else {
      #pragma unroll
      for (int rt=0;rt<4;rt++)
        #pragma unroll
        for (int i=0;i<4;i++){
          int nd = idxS[rt*16 + q*4 + i];
          if (nd >= 0) hOut[(size_t)nd*80 + 6 + u] = hreg[rt][i];
        }
    }
  }
}

// ======== wgemm: B-in-registers MFMA GEMM, up to 3 concatenated A segments =========
// LDS A-tile row stride padded +8 ushorts to break pow2 bank aliasing.
template<int RTR, int KT, int CT>
__global__ __launch_bounds__(256) void wgemm(
    const unsigned short* __restrict__ A0, int w0, int ldA0,
    const unsigned short* __restrict__ A1, int w1, int ldA1,
    const unsigned short* __restrict__ A2, int w2, int ldA2,
    const unsigned short* __restrict__ Bt, int KpB,
    const float* __restrict__ bias,
    unsigned short* __restrict__ C, int ldC,
    int rows, int tiles, int act)
{
  constexpr int Kpad = KT*32;
  constexpr int LD   = Kpad + 8;
  constexpr int NRT  = RTR/16;
  constexpr int CPT  = (RTR*Kpad/8)/256;
  __shared__ __align__(16) unsigned short As[2][RTR*LD];
  int t = threadIdx.x;
  int lane = t & 63, m = lane & 15, q = lane >> 4, w = t >> 6;
  int tileBase = blockIdx.y * (4*CT);
  int rtEnd = (rows + RTR - 1)/RTR;
  int tr = blockIdx.x;
  if (tr >= rtEnd) return;

  short8 breg[CT][KT]; float bv[CT]; bool val[CT]; int colr[CT];
  #pragma unroll
  for (int j=0;j<CT;j++){
    int tt = tileBase + w + 4*j;
    val[j] = (tt < tiles);
    int col = tt*16 + m;
    colr[j] = col;
    bv[j] = 0.f;
    if (val[j]){
      bv[j] = bias[col];
      #pragma unroll
      for (int kt=0;kt<KT;kt++)
        breg[j][kt] = *(const short8*)&Bt[(size_t)col*KpB + kt*32 + q*8];
    } else {
      #pragma unroll
      for (int kt=0;kt<KT;kt++) breg[j][kt] = (short8){0,0,0,0,0,0,0,0};
    }
  }

  int w01 = w0 + w1, w012 = w0 + w1 + w2;
  uint4 r[CPT];
  auto loadRegs = [&](int trr){
    #pragma unroll
    for (int i=0;i<CPT;i++){
      int c = i*256 + t;
      int row = c / (KT*4), kc = (c - row*(KT*4))*8;
      int gr = trr*RTR + row;
      uint4 v = {0,0,0,0};
      if (gr < rows && kc < w012){
        const unsigned short* sp;
        if (kc < w0)       sp = A0 + (size_t)gr*ldA0 + kc;
        else if (kc < w01) sp = A1 + (size_t)gr*ldA1 + (kc - w0);
        else               sp = A2 + (size_t)gr*ldA2 + (kc - w01);
        v = *(const uint4*)sp;
      }
      r[i] = v;
    }
  };
  auto dsw = [&](int p){
    #pragma unroll
    for (int i=0;i<CPT;i++){
      int c = i*256 + t;
      int row = c / (KT*4), kc = (c - row*(KT*4))*8;
      *(uint4*)&As[p][row*LD + kc] = r[i];
    }
  };

  loadRegs(tr);
  dsw(0);
  int p = 0;
  for (;;){
    int nxt = tr + gridDim.x;
    bool hasNext = (nxt < rtEnd);
    if (hasNext) loadRegs(nxt);
    __syncthreads();
    f32x4 acc[NRT][CT] = {};
    #pragma unroll
    for (int kt=0;kt<KT;kt++){
      short8 af[NRT];
      #pragma unroll
      for (int rt=0;rt<NRT;rt++)
        af[rt] = *(const short8*)&As[p][(rt*16+m)*LD + kt*32 + q*8];
      #pragma unroll
      for (int j=0;j<CT;j++)
        #pragma unroll
        for (int rt=0;rt<NRT;rt++)
          acc[rt][j] = __builtin_amdgcn_mfma_f32_16x16x32_bf16(af[rt], breg[j][kt], acc[rt][j], 0,0,0);
    }
    bool tfull = (tr*RTR + RTR <= rows);
#define EPILOG(CHK)                                                         \
    _Pragma("unroll")                                                       \
    for (int rt=0;rt<NRT;rt++){                                             \
      int rbase = tr*RTR + rt*16 + q*4;                                     \
      _Pragma("unroll")                                                     \
      for (int j=0;j<CT;j++){                                               \
        if (!val[j]) continue;                                              \
        _Pragma("unroll")                                                   \
        for (int i=0;i<4;i++){                                              \
          int grow = rbase + i;                                             \
          if (CHK && grow >= rows) continue;                                \
          float v = acc[rt][j][i] + bv[j];                                  \
          if (act == 1) v = fgelu_(v);                                      \
          else if (act == 2) v = ftanh_(v);                                 \
          C[(size_t)grow*ldC + colr[j]] = f2bf(v);                          \
        }                                                                   \
      }                                                                     \
    }
    if (tfull){ EPILOG(false) } else { EPILOG(true) }
#undef EPILOG
    if (!hasNext) break;
    dsw(p^1);
    p ^= 1; tr = nxt;
  }
}

// ---------------- CSR gather + segment max; padded int4 edata; WPN waves per node ----
__global__ __launch_bounds__(256) void k_aggregate(
    const int* __restrict__ off, const int* __restrict__ edata,
    const unsigned short* __restrict__ P2, int ldP, int off1,
    unsigned short* __restrict__ agg, int M, int N, int WPN)
{
  int t = threadIdx.x;
  int lane = t & 63, w = t >> 6;
  int node, c;
  if (WPN == 1){
    node = blockIdx.x*4 + w;
    c = 2*lane;
  } else {
    node = blockIdx.x*2 + (w >> 1);
    c = (w & 1)*80 + 2*lane;
  }
  if (node >= N || lane >= 40) return;
  int e0 = off[node], e1 = off[node+1];
  const float NEG = -__builtin_inff();
  float f0 = NEG, f1 = NEG;
  for (int e = e0; e < e1; e += 4){
    int4 w4 = *(const int4*)&edata[e];
    unsigned int u0 = *(const unsigned int*)(P2 + (size_t)(w4.x>>1)*ldP + (w4.x&1)*off1 + c);
    unsigned int u1 = *(const unsigned int*)(P2 + (size_t)(w4.y>>1)*ldP + (w4.y&1)*off1 + c);
    unsigned int u2 = *(const unsigned int*)(P2 + (size_t)(w4.z>>1)*ldP + (w4.z&1)*off1 + c);
    unsigned int u3 = *(const unsigned int*)(P2 + (size_t)(w4.w>>1)*ldP + (w4.w&1)*off1 + c);
    f0 = fmaxf(f0, fmaxf(fmaxf(__uint_as_float(u0<<16), __uint_as_float(u1<<16)),
                         fmaxf(__uint_as_float(u2<<16), __uint_as_float(u3<<16))));
    f1 = fmaxf(f1, fmaxf(fmaxf(__uint_as_float(u0&0xFFFF0000u), __uint_as_float(u1&0xFFFF0000u)),
                         fmaxf(__uint_as_float(u2&0xFFFF0000u), __uint_as_float(u3&0xFFFF0000u))));
  }
  unsigned int o = (__float_as_uint(f0 == NEG ? 0.f : f0) >> 16)
                 |  (__float_as_uint(f1 == NEG ? 0.f : f1) & 0xFFFF0000u);
  *(unsigned int*)(agg + (size_t)node*M + c) = o;
}

// ---------------- final head ----------------
__global__ void k_head(const unsigned short* __restrict__ h, const int* __restrict__ entry,
                       const float* __restrict__ W1, const float* __restrict__ b1,
                       const float* __restrict__ W2, const float* __restrict__ b2,
                       float* __restrict__ out){
  __shared__ float x[70], x1[70];
  int t = threadIdx.x;
  if (t < 70) x[t] = bf2f(h[(size_t)(*entry)*80 + t]);
  __syncthreads();
  if (t < 70){
    float s = b1[t];
    for (int i=0;i<70;i++) s += x[i]*W1[i*70 + t];
    x1[t] = fmaxf(s, 0.f);
  }
  __syncthreads();
  if (t < 640){
    float s = b2[t];
    for (int i=0;i<70;i++) s += x1[i]*W2[i*640 + t];
    out[t] = s;
  }
}

extern "C" void kernel_launch(void* const* d_in, const int* in_sizes, int n_in,
                              void* d_out, int out_size, void* d_ws, size_t ws_size,
                              hipStream_t stream) {
  const int*   tokens   = (const int*)d_in[0];
  const int*   type_idx = (const int*)d_in[1];
  const int*   esrc     = (const int*)d_in[2];
  const int*   edst     = (const int*)d_in[3];
  const int*   entry    = (const int*)d_in[4];
  const float* embed    = (const float*)d_in[5];
  const float* Wi_map   = (const float*)d_in[6];
  const float* Wh_map   = (const float*)d_in[7];
  const float* bi_map   = (const float*)d_in[8];
  const float* bh_map   = (const float*)d_in[9];
  const float* Wi_mem   = (const float*)d_in[10];
  const float* Wh_mem   = (const float*)d_in[11];
  const float* bi_mem   = (const float*)d_in[12];
  const float* bh_mem   = (const float*)d_in[13];
  const float* Wm_plain = (const float*)d_in[14];
  const float* bm_plain = (const float*)d_in[15];
  const float* Wu_plain = (const float*)d_in[16];
  const float* bu_plain = (const float*)d_in[17];
  const float* Wm_ar    = (const float*)d_in[18];
  const float* bm_ar    = (const float*)d_in[19];
  const float* Wu_ar    = (const float*)d_in[20];
  const float* bu_ar    = (const float*)d_in[21];
  const float* W1 = (const float*)d_in[22];
  const float* b1 = (const float*)d_in[23];
  const float* W2 = (const float*)d_in[24];
  const float* b2 = (const float*)d_in[25];
  float* out = (float*)d_out;

  const int N  = in_sizes[1];      // 100000
  const int TE = in_sizes[2];      // 500000
  const int E  = TE / 2;
  const int V64 = in_sizes[5];     // V*DE = 640000

  char* p = (char*)d_ws;
  auto alloc = [&](size_t bytes)->char* { char* r = p; p += (bytes + 255) & ~(size_t)255; return r; };
  unsigned short* hA  = (unsigned short*)alloc((size_t)N*80*2);
  unsigned short* hB  = (unsigned short*)alloc((size_t)N*80*2);
  unsigned short* hC  = (unsigned short*)alloc((size_t)N*80*2);
  unsigned short* P2  = (unsigned short*)alloc((size_t)N*320*2);
  unsigned short* agg = (unsigned short*)alloc((size_t)N*160*2);
  int* deg    = (int*)alloc((size_t)N*4);
  int* curp   = (int*)alloc((size_t)N*4);
  int* off    = (int*)alloc((size_t)(N+8)*4);
  int* edata  = (int*)alloc((size_t)(TE + 4*N + 16)*4);            // padded CSR
  int* sbsum  = (int*)alloc(256*4);
  int* cnt    = (int*)alloc(16*4);
  int* idxcat = (int*)alloc((size_t)R2*4);
  unsigned short* BtA  = (unsigned short*)alloc(388096*2);
  float* biasA = (float*)alloc(2752*4);
  unsigned short* embB = (unsigned short*)alloc((size_t)V64*2);

  hipMemsetAsync(idxcat, 0xFF, (size_t)R2*4, stream);
  hipMemsetAsync(cnt,    0,    16*4, stream);
  hipMemsetAsync(deg,    0,    (size_t)N*4, stream);
  hipMemsetAsync(curp,   0,    (size_t)N*4, stream);

  k_prepB<<<dim3(8,18), 256, 0, stream>>>(Wm_plain, Wu_plain, Wm_ar, Wu_ar,
                                          Wi_map, Wh_map, Wi_mem, Wh_mem, BtA);
  k_prepBias<<<1, 256, 0, stream>>>(bm_plain, bu_plain, bm_ar, bu_ar,
                                    bi_map, bh_map, bi_mem, bh_mem, biasA);
  k_prepEmb<<<(V64+255)/256, 256, 0, stream>>>(embed, embB, V64);
  k_init_h<<<(N*80+255)/256, 256, 0, stream>>>(type_idx, hA, N);
  k_compact<<<(N+255)/256, 256, 0, stream>>>(type_idx, idxcat, cnt, N);

  k_count<<<(TE+255)/256, 256, 0, stream>>>(edst, deg, TE);
  int nb = (N + 2047)/2048;
  k_scan1<<<nb, 256, 0, stream>>>(deg, off, sbsum, N);
  k_scan2<<<1, 64, 0, stream>>>(sbsum, nb);
  k_scan3<<<(N+255)/256, 256, 0, stream>>>(off, sbsum, N, nb);
  k_fill<<<(TE+255)/256, 256, 0, stream>>>(esrc, edst, off, curp, edata, TE, E);
  k_pad<<<(N+255)/256, 256, 0, stream>>>(off, curp, edata, N);

  // ---- GRU: one persistent launch (8 steps internal), gather+scatter fused ----
  kgru<<<dim3(CAPT/64, 2), 256, 0, stream>>>(
      idxcat, tokens, embB,
      BtA + 322560, BtA + 322560 + 32768,
      biasA + 2240, biasA + 2240 + 256, hA);

  // ---- 2 blocks x (3 plain MP + concat-residual AR MP) ----
  unsigned short* cur = hA; unsigned short* f1 = hB; unsigned short* f2 = hC;
  int li = 0;
  for (int blk = 0; blk < 2; blk++){
    unsigned short* saved = cur;
    unsigned short* ins[3]  = {cur, f1, f2};
    unsigned short* outs[3] = {f1, f2, f1};
    for (int j = 0; j < 3; j++){
      unsigned short* X = ins[j]; unsigned short* Yo = outs[j];
      // msg: [N,80] @ [96->160] (both edge types fused in cols)
      wgemm<64,3,3><<<dim3(1024,1), 256, 0, stream>>>(
          X, 80, 80,  nullptr, 0, 0,  nullptr, 0, 0,
          BtA + li*15360, 96, biasA + li*160,
          P2, 160, N, 10, 0);
      k_aggregate<<<(N+3)/4, 256, 0, stream>>>(off, edata, P2, 160, 80, agg, 80, N, 1);
      // upd: [N,80|80] @ [160->80]
      wgemm<64,5,2><<<dim3(1024,1), 256, 0, stream>>>(
          X, 80, 80,  agg, 80, 80,  nullptr, 0, 0,
          BtA + 92160 + li*12800, 160, biasA + 960 + li*80,
          Yo, 80, N, 5, 0);
      li++;
    }
    // AR msg: [N,80|80] @ [160->320], gelu; y splits 20 col tiles into 12+8
    wgemm<64,5,3><<<dim3(512,2), 256, 0, stream>>>(
        saved, 80, 80,  f1, 80, 80,  nullptr, 0, 0,
        BtA + 168960 + blk*51200, 160, biasA + 1440 + blk*320,
        P2, 320, N, 20, 1 /*gelu*/);
    k_aggregate<<<(N+1)/2, 256, 0, stream>>>(off, edata, P2, 320, 160, agg, 160, N, 2);
    // AR upd: [N,80|80|160] @ [320->80], tanh; 32-row tiles (K=320 LDS)
    wgemm<32,10,2><<<dim3(1024,1), 256, 0, stream>>>(
        saved, 80, 80,  f1, 80, 80,  agg, 160, 160,
        BtA + 271360 + blk*25600, 320, biasA + 2080 + blk*80,
        f2, 80, N, 5, 2 /*tanh*/);
    unsigned short* t3 = cur; cur = f2; f2 = t3;
  }

  k_head<<<1, 640, 0, stream>>>(cur, entry, W1, b1, W2, b2, out);
}

// Round 10
// 935.941 us; speedup vs baseline: 1.2607x; 1.0770x over previous
//
#include <hip/hip_runtime.h>
#include <math.h>

#define CAPT 20480              // per-type compacted-node capacity (actual ~16.7k)
#define R2   (2*CAPT)
#define GLD  136                // kgru LDS row stride (ushorts): breaks pow2 banking

typedef __attribute__((ext_vector_type(8))) short short8;
typedef __attribute__((ext_vector_type(4))) float f32x4;

// ---- fast transcendentals: v_exp_f32 / v_rcp_f32 based; err ~1e-7 << bf16 ulp ----
__device__ __forceinline__ float fexp2_(float x){ return __builtin_amdgcn_exp2f(x); }
__device__ __forceinline__ float frcp_(float x){ return __builtin_amdgcn_rcpf(x); }
__device__ __forceinline__ float ftanh_(float x){
  float ax = __builtin_fabsf(x);
  float t = fexp2_(-2.885390082f * ax);          // e^{-2|x|}
  float r = (1.f - t) * frcp_(1.f + t);
  return __builtin_copysignf(r, x);
}
__device__ __forceinline__ float fsig_(float x){
  return frcp_(1.f + fexp2_(-1.442695041f * x));
}
__device__ __forceinline__ float fgelu_(float x){
  const float c = 0.7978845608028654f;
  return 0.5f*x*(1.f + ftanh_(c*(x + 0.044715f*x*x*x)));
}
__device__ __forceinline__ unsigned short f2bf(float x){
  unsigned int u = __float_as_uint(x);
  return (unsigned short)((u + 0x7FFFu + ((u>>16)&1u)) >> 16);
}
__device__ __forceinline__ float bf2f(unsigned short v){
  return __uint_as_float(((unsigned int)v) << 16);
}

// ---------------- weight prep: transposed bf16 B arena, padded to 16-mult segments ----
// Arena layout (bf16 elems):
//  [0..6)      plain msg li:  [160][96]   off = li*15360
//  [6..12)     plain upd li:  [80][160]   off = 92160 + li*12800
//  [12..14)    ar msg blk:    [320][160]  off = 168960 + blk*51200
//  [14..16)    ar upd blk:    [80][320]   off = 271360 + blk*25600
//  [16..18)    gru typ:       [256][128]  off = 322560 + typ*32768
__global__ void k_prepB(const float* __restrict__ Wm_plain, const float* __restrict__ Wu_plain,
                        const float* __restrict__ Wm_ar, const float* __restrict__ Wu_ar,
                        const float* __restrict__ Wi_map, const float* __restrict__ Wh_map,
                        const float* __restrict__ Wi_mem, const float* __restrict__ Wh_mem,
                        unsigned short* __restrict__ BtArena){
  int id = blockIdx.y;
  int Kp, elems, off;
  if (id < 6){ Kp=96;  elems=15360; off=id*15360; }
  else if (id < 12){ Kp=160; elems=12800; off=92160+(id-6)*12800; }
  else if (id < 14){ Kp=160; elems=51200; off=168960+(id-12)*51200; }
  else if (id < 16){ Kp=320; elems=25600; off=271360+(id-14)*25600; }
  else { Kp=128; elems=32768; off=322560+(id-16)*32768; }
  for (int g = blockIdx.x*256 + threadIdx.x; g < elems; g += 8*256){
    int c = g / Kp, k = g - c*Kp;
    float val = 0.f;
    if (id < 6){
      int li = id; int t = (c >= 80); int cc = c - t*80;
      if (cc < 70 && k < 70) val = Wm_plain[((li*2+t)*70 + k)*70 + cc];
    } else if (id < 12){
      int li = id-6;
      int kk = (k < 70) ? k : ((k >= 80 && k < 150) ? 70 + (k-80) : -1);
      if (c < 70 && kk >= 0) val = Wu_plain[(li*140 + kk)*70 + c];
    } else if (id < 14){
      int blk = id-12; int t = (c >= 160); int cc = c - t*160;
      int kk = (k < 70) ? k : ((k >= 80 && k < 150) ? 70 + (k-80) : -1);
      if (cc < 140 && kk >= 0) val = Wm_ar[(((blk*2+t)*140) + kk)*140 + cc];
    } else if (id < 16){
      int blk = id-14;
      int kk = (k < 70) ? k : ((k >= 80 && k < 150) ? 70 + (k-80)
               : ((k >= 160 && k < 300) ? 140 + (k-160) : -1));
      if (c < 70 && kk >= 0) val = Wu_ar[(blk*280 + kk)*70 + c];
    } else {
      int typ = id-16;
      const float* Wi = typ ? Wi_mem : Wi_map;
      const float* Wh = typ ? Wh_mem : Wh_map;
      if (c < 192) val = (k < 64) ? Wi[c*64 + k] : Wh[c*64 + (k-64)];
      else { int cc = c-192; val = (k >= 64) ? Wh[(128+cc)*64 + (k-64)] : 0.f; }
    }
    BtArena[off + g] = f2bf(val);
  }
}

// bias arena (fp32): [0..960) plain msg [160]x6; [960..1440) plain upd [80]x6;
// [1440..2080) ar msg [320]x2; [2080..2240) ar upd [80]x2; [2240..2752) gru [256]x2
__global__ void k_prepBias(const float* __restrict__ bm_plain, const float* __restrict__ bu_plain,
                           const float* __restrict__ bm_ar, const float* __restrict__ bu_ar,
                           const float* __restrict__ bi_map, const float* __restrict__ bh_map,
                           const float* __restrict__ bi_mem, const float* __restrict__ bh_mem,
                           float* __restrict__ biasA){
  for (int g = threadIdx.x; g < 2752; g += 256){
    float val = 0.f;
    if (g < 960){ int li=g/160, c=g%160; int t=(c>=80); int cc=c-t*80;
      if (cc<70) val = bm_plain[(li*2+t)*70 + cc]; }
    else if (g < 1440){ int u=g-960; int li=u/80, c=u%80; if (c<70) val = bu_plain[li*70+c]; }
    else if (g < 2080){ int u=g-1440; int blk=u/320, c=u%320; int t=(c>=160); int cc=c-t*160;
      if (cc<140) val = bm_ar[(blk*2+t)*140 + cc]; }
    else if (g < 2240){ int u=g-2080; int blk=u/80, c=u%80; if (c<70) val = bu_ar[blk*70+c]; }
    else { int u=g-2240; int typ=u/256, c=u%256;
      const float* bi = typ ? bi_mem : bi_map; const float* bh = typ ? bh_mem : bh_map;
      val = (c < 192) ? (bi[c]+bh[c]) : bh[128 + (c-192)]; }
    biasA[g] = val;
  }
}

// ---------------- embed -> bf16 table (1.28 MB, L2-resident for the gather) ----------
__global__ void k_prepEmb(const float* __restrict__ embed, unsigned short* __restrict__ embB,
                          int total){
  int g = blockIdx.x*256 + threadIdx.x;
  if (g < total) embB[g] = f2bf(embed[g]);
}

// ---------------- init h = [one_hot(type,6) | zeros] bf16, stride 80 ----------------
__global__ void k_init_h(const int* __restrict__ type_idx, unsigned short* __restrict__ h, int N){
  int g = blockIdx.x*256 + threadIdx.x;
  if (g >= N*80) return;
  int n = g / 80, c = g - n*80;
  h[g] = (c < 6 && type_idx[n] == c) ? (unsigned short)0x3F80 : (unsigned short)0;
}

__global__ void k_compact(const int* __restrict__ type_idx, int* __restrict__ idxcat,
                          int* __restrict__ cnt, int N){
  int n = blockIdx.x*256 + threadIdx.x;
  if (n >= N) return;
  int t = type_idx[n];
  if (t == 0){ int p = atomicAdd(&cnt[0],1); if (p < CAPT) idxcat[p] = n; }
  else if (t == 5){ int p = atomicAdd(&cnt[1],1); if (p < CAPT) idxcat[CAPT+p] = n; }
}

// ---------------- CSR build, per-node edge count padded to multiple of 4 -------------
__global__ void k_count(const int* __restrict__ edst, int* __restrict__ deg, int TE){
  int i = blockIdx.x*256 + threadIdx.x;
  if (i < TE) atomicAdd(&deg[edst[i]], 1);
}
__global__ void k_scan1(const int* __restrict__ deg, int* __restrict__ off,
                        int* __restrict__ bsum, int N){
  __shared__ int sh[256];
  int t = threadIdx.x; int base = blockIdx.x*2048;
  int v[8]; int s = 0;
  for (int i=0;i<8;i++){
    int g = base + t*8 + i;
    int x = (g<N)? (((deg[g]+3)>>2)<<2) : 0;     // pad to x4
    v[i]=x; s+=x;
  }
  sh[t]=s; __syncthreads();
  for (int o=1;o<256;o<<=1){ int x = (t>=o)? sh[t-o]:0; __syncthreads(); sh[t]+=x; __syncthreads(); }
  if (t==255) bsum[blockIdx.x] = sh[255];
  int run = sh[t]-s;
  for (int i=0;i<8;i++){ int g = base + t*8 + i; if (g<N) off[g]=run; run+=v[i]; }
}
__global__ void k_scan2(int* bsum, int nb){
  if (threadIdx.x==0 && blockIdx.x==0){
    int run=0;
    for(int b=0;b<nb;b++){ int x=bsum[b]; bsum[b]=run; run+=x; }
    bsum[nb]=run;                                 // grand total (padded)
  }
}
__global__ void k_scan3(int* __restrict__ off, const int* __restrict__ bsum, int N, int nb){
  int g = blockIdx.x*256+threadIdx.x;
  if (g < N) off[g] += bsum[g>>11];
  if (g == 0) off[N] = bsum[nb];
}
__global__ void k_fill(const int* __restrict__ esrc, const int* __restrict__ edst,
                       const int* __restrict__ off, int* __restrict__ cur,
                       int* __restrict__ edata, int TE, int E){
  int i = blockIdx.x*256 + threadIdx.x;
  if (i >= TE) return;
  int d = edst[i];
  int pos = off[d] + atomicAdd(&cur[d], 1);
  edata[pos] = (esrc[i] << 1) | (i >= E ? 1 : 0);
}
// pad slots [deg, deg4) with a duplicate of the node's first edge (idempotent for max)
__global__ void k_pad(const int* __restrict__ off, const int* __restrict__ cur,
                      int* __restrict__ edata, int N){
  int n = blockIdx.x*256 + threadIdx.x;
  if (n >= N) return;
  int d = cur[n];
  if (d == 0) return;
  int d4 = ((d+3)>>2)<<2;
  int base = off[n];
  int first = edata[base];
  for (int i = d; i < d4; i++) edata[base+i] = first;
}

// ======== kgru v2: persistent GRU — padded LDS stride, double buffer, 1 barrier/step
__global__ __launch_bounds__(256) void kgru(
    const int* __restrict__ idxcat, const int* __restrict__ tokens,
    const unsigned short* __restrict__ embB,
    const unsigned short* __restrict__ Bt, const unsigned short* __restrict__ Bt2,
    const float* __restrict__ bias, const float* __restrict__ bias2,
    unsigned short* __restrict__ hOut)
{
  __shared__ __align__(16) unsigned short As[2][64*GLD];
  __shared__ int tokS[64*8];
  __shared__ int idxS[64];
  int rb = blockIdx.y * CAPT + blockIdx.x * 64;
  if (idxcat[rb] < 0) return;                      // all-pad block
  int t = threadIdx.x;
  int lane = t & 63, m = lane & 15, q = lane >> 4, w = t >> 6;
  const unsigned short* Bsel = blockIdx.y ? Bt2 : Bt;
  const float* bsel = blockIdx.y ? bias2 : bias;
  short8 breg[4][4]; float bv[4];
  #pragma unroll
  for (int j=0;j<4;j++){
    int col = (w + 4*j)*16 + m;
    bv[j] = bsel[col];
    #pragma unroll
    for (int kt=0;kt<4;kt++)
      breg[j][kt] = *(const short8*)&Bsel[(size_t)col*128 + kt*32 + q*8];
  }
  if (t < 64) idxS[t] = idxcat[rb + t];
  for (int j = t; j < 512; j += 256){
    int nd = idxcat[rb + (j>>3)]; if (nd < 0) nd = 0;
    tokS[j] = tokens[nd*8 + (j & 7)];
  }
  __syncthreads();                                 // tokS ready
  for (int j = t; j < 512; j += 256){
    int row = j >> 3, ch = j & 7;
    *(uint4*)&As[0][row*GLD + ch*8] = *(const uint4*)&embB[(size_t)tokS[row*8]*64 + ch*8];
  }
  for (int j = t; j < 2048; j += 256){
    int row = j >> 5, k2 = (j & 31)*2;
    *(unsigned int*)&As[0][row*GLD + 64 + k2] = 0;
  }
  __syncthreads();
  unsigned short hreg[4][4];
  #pragma unroll
  for (int rt=0;rt<4;rt++)
    #pragma unroll
    for (int i=0;i<4;i++) hreg[rt][i] = 0;
  int u = w*16 + m;
  int p = 0;
  for (int s = 0; s < 8; s++){
    uint4 xr[2];
    if (s < 7){                                    // prefetch X(s+1) early (global)
      #pragma unroll
      for (int i=0;i<2;i++){
        int j = t + i*256;
        int row = j >> 3, ch = j & 7;
        xr[i] = *(const uint4*)&embB[(size_t)tokS[row*8 + s + 1]*64 + ch*8];
      }
    }
    f32x4 acc[4][4] = {};
    #pragma unroll
    for (int kt=0;kt<4;kt++){
      short8 af[4];
      #pragma unroll
      for (int rt=0;rt<4;rt++)
        af[rt] = *(const short8*)&As[p][(rt*16+m)*GLD + kt*32 + q*8];
      #pragma unroll
      for (int j=0;j<4;j++)
        #pragma unroll
        for (int rt=0;rt<4;rt++)
          acc[rt][j] = __builtin_amdgcn_mfma_f32_16x16x32_bf16(af[rt], breg[j][kt], acc[rt][j], 0,0,0);
    }
    #pragma unroll
    for (int rt=0;rt<4;rt++){
      #pragma unroll
      for (int i=0;i<4;i++){
        float rr = fsig_(acc[rt][0][i] + bv[0]);
        float zz = fsig_(acc[rt][1][i] + bv[1]);
        float hn = acc[rt][3][i] + bv[3];
        float nn = ftanh_(acc[rt][2][i] + bv[2] + (rr - 1.f)*hn);
        float hp = bf2f(hreg[rt][i]);
        hreg[rt][i] = f2bf((1.f - zz)*nn + zz*hp);
      }
    }
    if (s < 7){
      #pragma unroll
      for (int rt=0;rt<4;rt++)
        #pragma unroll
        for (int i=0;i<4;i++)
          As[p^1][(rt*16 + q*4 + i)*GLD + 64 + u] = hreg[rt][i];
      #pragma unroll
      for (int i=0;i<2;i++){
        int j = t + i*256;
        int row = j >> 3, ch = j & 7;
        *(uint4*)&As[p^1][row*GLD + ch*8] = xr[i];
      }
      __syncthreads();
      p ^= 1;
    } else {
      #pragma unroll
      for (int rt=0;rt<4;rt++)
        #pragma unroll
        for (int i=0;i<4;i++){
          int nd = idxS[rt*16 + q*4 + i];
          if (nd >= 0) hOut[(size_t)nd*80 + 6 + u] = hreg[rt][i];
        }
    }
  }
}

// ======== wgemm: B-in-registers MFMA GEMM, up to 3 concatenated A segments =========
template<int RTR, int KT, int CT>
__global__ __launch_bounds__(256) void wgemm(
    const unsigned short* __restrict__ A0, int w0, int ldA0,
    const unsigned short* __restrict__ A1, int w1, int ldA1,
    const unsigned short* __restrict__ A2, int w2, int ldA2,
    const unsigned short* __restrict__ Bt, int KpB,
    const float* __restrict__ bias,
    unsigned short* __restrict__ C, int ldC,
    int rows, int tiles, int act)
{
  constexpr int Kpad = KT*32;
  constexpr int LD   = Kpad + 8;
  constexpr int NRT  = RTR/16;
  constexpr int CPT  = (RTR*Kpad/8)/256;
  __shared__ __align__(16) unsigned short As[2][RTR*LD];
  int t = threadIdx.x;
  int lane = t & 63, m = lane & 15, q = lane >> 4, w = t >> 6;
  int tileBase = blockIdx.y * (4*CT);
  int rtEnd = (rows + RTR - 1)/RTR;
  int tr = blockIdx.x;
  if (tr >= rtEnd) return;

  short8 breg[CT][KT]; float bv[CT]; bool val[CT]; int colr[CT];
  #pragma unroll
  for (int j=0;j<CT;j++){
    int tt = tileBase + w + 4*j;
    val[j] = (tt < tiles);
    int col = tt*16 + m;
    colr[j] = col;
    bv[j] = 0.f;
    if (val[j]){
      bv[j] = bias[col];
      #pragma unroll
      for (int kt=0;kt<KT;kt++)
        breg[j][kt] = *(const short8*)&Bt[(size_t)col*KpB + kt*32 + q*8];
    } else {
      #pragma unroll
      for (int kt=0;kt<KT;kt++) breg[j][kt] = (short8){0,0,0,0,0,0,0,0};
    }
  }

  int w01 = w0 + w1, w012 = w0 + w1 + w2;
  uint4 r[CPT];
  auto loadRegs = [&](int trr){
    #pragma unroll
    for (int i=0;i<CPT;i++){
      int c = i*256 + t;
      int row = c / (KT*4), kc = (c - row*(KT*4))*8;
      int gr = trr*RTR + row;
      uint4 v = {0,0,0,0};
      if (gr < rows && kc < w012){
        const unsigned short* sp;
        if (kc < w0)       sp = A0 + (size_t)gr*ldA0 + kc;
        else if (kc < w01) sp = A1 + (size_t)gr*ldA1 + (kc - w0);
        else               sp = A2 + (size_t)gr*ldA2 + (kc - w01);
        v = *(const uint4*)sp;
      }
      r[i] = v;
    }
  };
  auto dsw = [&](int p){
    #pragma unroll
    for (int i=0;i<CPT;i++){
      int c = i*256 + t;
      int row = c / (KT*4), kc = (c - row*(KT*4))*8;
      *(uint4*)&As[p][row*LD + kc] = r[i];
    }
  };

  loadRegs(tr);
  dsw(0);
  int p = 0;
  for (;;){
    int nxt = tr + gridDim.x;
    bool hasNext = (nxt < rtEnd);
    if (hasNext) loadRegs(nxt);
    __syncthreads();
    f32x4 acc[NRT][CT] = {};
    #pragma unroll
    for (int kt=0;kt<KT;kt++){
      short8 af[NRT];
      #pragma unroll
      for (int rt=0;rt<NRT;rt++)
        af[rt] = *(const short8*)&As[p][(rt*16+m)*LD + kt*32 + q*8];
      #pragma unroll
      for (int j=0;j<CT;j++)
        #pragma unroll
        for (int rt=0;rt<NRT;rt++)
          acc[rt][j] = __builtin_amdgcn_mfma_f32_16x16x32_bf16(af[rt], breg[j][kt], acc[rt][j], 0,0,0);
    }
    bool tfull = (tr*RTR + RTR <= rows);
#define EPILOG(CHK)                                                         \
    _Pragma("unroll")                                                       \
    for (int rt=0;rt<NRT;rt++){                                             \
      int rbase = tr*RTR + rt*16 + q*4;                                     \
      _Pragma("unroll")                                                     \
      for (int j=0;j<CT;j++){                                               \
        if (!val[j]) continue;                                              \
        _Pragma("unroll")                                                   \
        for (int i=0;i<4;i++){                                              \
          int grow = rbase + i;                                             \
          if (CHK && grow >= rows) continue;                                \
          float v = acc[rt][j][i] + bv[j];                                  \
          if (act == 1) v = fgelu_(v);                                      \
          else if (act == 2) v = ftanh_(v);                                 \
          C[(size_t)grow*ldC + colr[j]] = f2bf(v);                          \
        }                                                                   \
      }                                                                     \
    }
    if (tfull){ EPILOG(false) } else { EPILOG(true) }
#undef EPILOG
    if (!hasNext) break;
    dsw(p^1);
    p ^= 1; tr = nxt;
  }
}

// ---------------- CSR gather + segment max; SCALARIZED node/edge addressing ---------
// node forced wave-uniform via readfirstlane -> off/edata loads become s_loads and
// row-base math runs on the scalar pipe; VALU only does unpack+max.
__global__ __launch_bounds__(256) void k_aggregate(
    const int* __restrict__ off, const int* __restrict__ edata,
    const unsigned short* __restrict__ P2, int ldP, int off1,
    unsigned short* __restrict__ agg, int M, int N, int WPN)
{
  int t = threadIdx.x;
  int lane = t & 63, w = t >> 6;
  int node, c;
  if (WPN == 1){
    node = blockIdx.x*4 + w;
    c = 2*lane;
  } else {
    node = blockIdx.x*2 + (w >> 1);
    c = (w & 1)*80 + 2*lane;
  }
  node = __builtin_amdgcn_readfirstlane(node);   // wave-uniform in truth; force SGPR
  if (node >= N) return;
  bool act = (lane < 40);
  int e0 = __builtin_amdgcn_readfirstlane(off[node]);
  int e1 = __builtin_amdgcn_readfirstlane(off[node+1]);
  const float NEG = -__builtin_inff();
  float f0 = NEG, f1 = NEG;
  for (int e = e0; e < e1; e += 4){
    int4 w4 = *(const int4*)&edata[e];           // uniform addr -> s_load_dwordx4
    int b0 = (w4.x>>1)*ldP + (w4.x&1)*off1;      // scalar-pipe math
    int b1 = (w4.y>>1)*ldP + (w4.y&1)*off1;
    int b2 = (w4.z>>1)*ldP + (w4.z&1)*off1;
    int b3 = (w4.w>>1)*ldP + (w4.w&1)*off1;
    if (act){
      unsigned int u0 = *(const unsigned int*)(P2 + b0 + c);
      unsigned int u1 = *(const unsigned int*)(P2 + b1 + c);
      unsigned int u2 = *(const unsigned int*)(P2 + b2 + c);
      unsigned int u3 = *(const unsigned int*)(P2 + b3 + c);
      f0 = fmaxf(f0, fmaxf(fmaxf(__uint_as_float(u0<<16), __uint_as_float(u1<<16)),
                           fmaxf(__uint_as_float(u2<<16), __uint_as_float(u3<<16))));
      f1 = fmaxf(f1, fmaxf(fmaxf(__uint_as_float(u0&0xFFFF0000u), __uint_as_float(u1&0xFFFF0000u)),
                           fmaxf(__uint_as_float(u2&0xFFFF0000u), __uint_as_float(u3&0xFFFF0000u))));
    }
  }
  if (act){
    unsigned int o = (__float_as_uint(f0 == NEG ? 0.f : f0) >> 16)
                   |  (__float_as_uint(f1 == NEG ? 0.f : f1) & 0xFFFF0000u);
    *(unsigned int*)(agg + (size_t)node*M + c) = o;
  }
}

// ---------------- final head ----------------
__global__ void k_head(const unsigned short* __restrict__ h, const int* __restrict__ entry,
                       const float* __restrict__ W1, const float* __restrict__ b1,
                       const float* __restrict__ W2, const float* __restrict__ b2,
                       float* __restrict__ out){
  __shared__ float x[70], x1[70];
  int t = threadIdx.x;
  if (t < 70) x[t] = bf2f(h[(size_t)(*entry)*80 + t]);
  __syncthreads();
  if (t < 70){
    float s = b1[t];
    for (int i=0;i<70;i++) s += x[i]*W1[i*70 + t];
    x1[t] = fmaxf(s, 0.f);
  }
  __syncthreads();
  if (t < 640){
    float s = b2[t];
    for (int i=0;i<70;i++) s += x1[i]*W2[i*640 + t];
    out[t] = s;
  }
}

extern "C" void kernel_launch(void* const* d_in, const int* in_sizes, int n_in,
                              void* d_out, int out_size, void* d_ws, size_t ws_size,
                              hipStream_t stream) {
  const int*   tokens   = (const int*)d_in[0];
  const int*   type_idx = (const int*)d_in[1];
  const int*   esrc     = (const int*)d_in[2];
  const int*   edst     = (const int*)d_in[3];
  const int*   entry    = (const int*)d_in[4];
  const float* embed    = (const float*)d_in[5];
  const float* Wi_map   = (const float*)d_in[6];
  const float* Wh_map   = (const float*)d_in[7];
  const float* bi_map   = (const float*)d_in[8];
  const float* bh_map   = (const float*)d_in[9];
  const float* Wi_mem   = (const float*)d_in[10];
  const float* Wh_mem   = (const float*)d_in[11];
  const float* bi_mem   = (const float*)d_in[12];
  const float* bh_mem   = (const float*)d_in[13];
  const float* Wm_plain = (const float*)d_in[14];
  const float* bm_plain = (const float*)d_in[15];
  const float* Wu_plain = (const float*)d_in[16];
  const float* bu_plain = (const float*)d_in[17];
  const float* Wm_ar    = (const float*)d_in[18];
  const float* bm_ar    = (const float*)d_in[19];
  const float* Wu_ar    = (const float*)d_in[20];
  const float* bu_ar    = (const float*)d_in[21];
  const float* W1 = (const float*)d_in[22];
  const float* b1 = (const float*)d_in[23];
  const float* W2 = (const float*)d_in[24];
  const float* b2 = (const float*)d_in[25];
  float* out = (float*)d_out;

  const int N  = in_sizes[1];      // 100000
  const int TE = in_sizes[2];      // 500000
  const int E  = TE / 2;
  const int V64 = in_sizes[5];     // V*DE = 640000

  char* p = (char*)d_ws;
  auto alloc = [&](size_t bytes)->char* { char* r = p; p += (bytes + 255) & ~(size_t)255; return r; };
  unsigned short* hA  = (unsigned short*)alloc((size_t)N*80*2);
  unsigned short* hB  = (unsigned short*)alloc((size_t)N*80*2);
  unsigned short* hC  = (unsigned short*)alloc((size_t)N*80*2);
  unsigned short* P2  = (unsigned short*)alloc((size_t)N*320*2);
  unsigned short* agg = (unsigned short*)alloc((size_t)N*160*2);
  int* deg    = (int*)alloc((size_t)N*4);
  int* curp   = (int*)alloc((size_t)N*4);
  int* off    = (int*)alloc((size_t)(N+8)*4);
  int* edata  = (int*)alloc((size_t)(TE + 4*N + 16)*4);            // padded CSR
  int* sbsum  = (int*)alloc(256*4);
  int* cnt    = (int*)alloc(16*4);
  int* idxcat = (int*)alloc((size_t)R2*4);
  unsigned short* BtA  = (unsigned short*)alloc(388096*2);
  float* biasA = (float*)alloc(2752*4);
  unsigned short* embB = (unsigned short*)alloc((size_t)V64*2);

  hipMemsetAsync(idxcat, 0xFF, (size_t)R2*4, stream);
  hipMemsetAsync(cnt,    0,    16*4, stream);
  hipMemsetAsync(deg,    0,    (size_t)N*4, stream);
  hipMemsetAsync(curp,   0,    (size_t)N*4, stream);

  k_prepB<<<dim3(8,18), 256, 0, stream>>>(Wm_plain, Wu_plain, Wm_ar, Wu_ar,
                                          Wi_map, Wh_map, Wi_mem, Wh_mem, BtA);
  k_prepBias<<<1, 256, 0, stream>>>(bm_plain, bu_plain, bm_ar, bu_ar,
                                    bi_map, bh_map, bi_mem, bh_mem, biasA);
  k_prepEmb<<<(V64+255)/256, 256, 0, stream>>>(embed, embB, V64);
  k_init_h<<<(N*80+255)/256, 256, 0, stream>>>(type_idx, hA, N);
  k_compact<<<(N+255)/256, 256, 0, stream>>>(type_idx, idxcat, cnt, N);

  k_count<<<(TE+255)/256, 256, 0, stream>>>(edst, deg, TE);
  int nb = (N + 2047)/2048;
  k_scan1<<<nb, 256, 0, stream>>>(deg, off, sbsum, N);
  k_scan2<<<1, 64, 0, stream>>>(sbsum, nb);
  k_scan3<<<(N+255)/256, 256, 0, stream>>>(off, sbsum, N, nb);
  k_fill<<<(TE+255)/256, 256, 0, stream>>>(esrc, edst, off, curp, edata, TE, E);
  k_pad<<<(N+255)/256, 256, 0, stream>>>(off, curp, edata, N);

  // ---- GRU: one persistent launch (8 steps internal), gather+scatter fused ----
  kgru<<<dim3(CAPT/64, 2), 256, 0, stream>>>(
      idxcat, tokens, embB,
      BtA + 322560, BtA + 322560 + 32768,
      biasA + 2240, biasA + 2240 + 256, hA);

  // ---- 2 blocks x (3 plain MP + concat-residual AR MP) ----
  unsigned short* cur = hA; unsigned short* f1 = hB; unsigned short* f2 = hC;
  int li = 0;
  for (int blk = 0; blk < 2; blk++){
    unsigned short* saved = cur;
    unsigned short* ins[3]  = {cur, f1, f2};
    unsigned short* outs[3] = {f1, f2, f1};
    for (int j = 0; j < 3; j++){
      unsigned short* X = ins[j]; unsigned short* Yo = outs[j];
      // msg: [N,80] @ [96->160] (both edge types fused in cols)
      wgemm<64,3,3><<<dim3(1024,1), 256, 0, stream>>>(
          X, 80, 80,  nullptr, 0, 0,  nullptr, 0, 0,
          BtA + li*15360, 96, biasA + li*160,
          P2, 160, N, 10, 0);
      k_aggregate<<<(N+3)/4, 256, 0, stream>>>(off, edata, P2, 160, 80, agg, 80, N, 1);
      // upd: [N,80|80] @ [160->80]
      wgemm<64,5,2><<<dim3(1024,1), 256, 0, stream>>>(
          X, 80, 80,  agg, 80, 80,  nullptr, 0, 0,
          BtA + 92160 + li*12800, 160, biasA + 960 + li*80,
          Yo, 80, N, 5, 0);
      li++;
    }
    // AR msg: [N,80|80] @ [160->320], gelu; y splits 20 col tiles into 12+8
    wgemm<64,5,3><<<dim3(512,2), 256, 0, stream>>>(
        saved, 80, 80,  f1, 80, 80,  nullptr, 0, 0,
        BtA + 168960 + blk*51200, 160, biasA + 1440 + blk*320,
        P2, 320, N, 20, 1 /*gelu*/);
    k_aggregate<<<(N+1)/2, 256, 0, stream>>>(off, edata, P2, 320, 160, agg, 160, N, 2);
    // AR upd: [N,80|80|160] @ [320->80], tanh; 32-row tiles (K=320 LDS)
    wgemm<32,10,2><<<dim3(1024,1), 256, 0, stream>>>(
        saved, 80, 80,  f1, 80, 80,  agg, 160, 160,
        BtA + 271360 + blk*25600, 320, biasA + 2080 + blk*80,
        f2, 80, N, 5, 2 /*tanh*/);
    unsigned short* t3 = cur; cur = f2; f2 = t3;
  }

  k_head<<<1, 640, 0, stream>>>(cur, entry, W1, b1, W2, b2, out);
}